// Round 13
// baseline (325.296 us; speedup 1.0000x reference)
//
#include <hip/hip_runtime.h>

#define IN_DIM 128
#define F1 256      // HEADS*HID = 4*64
#define HID 64
#define OUT_DIM 32
#define NEG 0.2f
#define PADK 136    // LDS row pitch in bf16 elems (128 + 8): frag reads 2-way alias = free

typedef __attribute__((ext_vector_type(8))) short short8;
typedef __attribute__((ext_vector_type(4))) float v4f;
typedef __attribute__((ext_vector_type(2))) float v2f;

// ---- bf16 helpers ----
__device__ __forceinline__ float b2fl(unsigned u) {
  union { unsigned i; float f; } c; c.i = u << 16; return c.f;
}
__device__ __forceinline__ float b2fh(unsigned u) {
  union { unsigned i; float f; } c; c.i = u & 0xffff0000u; return c.f;
}
__device__ __forceinline__ unsigned short f2b(float f) {
  union { float f; unsigned i; } c; c.f = f;
  unsigned r = c.i + 0x7fffu + ((c.i >> 16) & 1u);   // RNE
  return (unsigned short)(r >> 16);
}

// ---- prep: W1t[n][k] bf16 = transpose of W1[k][n] fp32 (one-time, 32K elems) ----
__global__ __launch_bounds__(256) void k_prep(const float* __restrict__ W1,
    unsigned short* __restrict__ W1t) {
  int idx = blockIdx.x * 256 + threadIdx.x;   // 0..32767
  int nn = idx >> 7, k = idx & 127;
  W1t[idx] = f2b(W1[(size_t)k * F1 + nn]);
}

// ------- GEMM1 via MFMA: h1f8[N,256](fp8 e4m3) = bf16(x)[N,128] @ W1[128,256] -------
__global__ __launch_bounds__(256) void k_gemm1(const float* __restrict__ x,
    const unsigned short* __restrict__ W1t,
    const float* __restrict__ a1s_w, const float* __restrict__ a1d_w,
    unsigned char* __restrict__ h1f8, float* __restrict__ as1,
    float* __restrict__ ad1, int n) {
  __shared__ unsigned short xs[64 * PADK];   // 17.4 KB
  __shared__ unsigned short ws[64 * PADK];   // 17.4 KB
  const int tid = threadIdx.x;
  const int rb = blockIdx.x * 64;
  const int head = blockIdx.y;
  const int cb = head * 64;

#pragma unroll
  for (int i = 0; i < 8; ++i) {
    int idx = tid + i * 256;
    int row = idx >> 5, c4 = idx & 31;
    float4 v = make_float4(0.f, 0.f, 0.f, 0.f);
    if (rb + row < n) v = *(const float4*)&x[(size_t)(rb + row) * IN_DIM + c4 * 4];
    ushort4 b; b.x = f2b(v.x); b.y = f2b(v.y); b.z = f2b(v.z); b.w = f2b(v.w);
    *(ushort4*)&xs[row * PADK + c4 * 4] = b;
  }
#pragma unroll
  for (int i = 0; i < 4; ++i) {
    int idx = tid + i * 256;
    int row = idx >> 4, c = idx & 15;
    *(uint4*)&ws[row * PADK + c * 8] =
        *(const uint4*)&W1t[(size_t)(cb + row) * IN_DIM + c * 8];
  }
  __syncthreads();

  const int wv = tid >> 6;
  const int lane = tid & 63;
  const int l15 = lane & 15, quad = lane >> 4;
  v4f acc0 = {0.f, 0.f, 0.f, 0.f}, acc1 = acc0, acc2 = acc0, acc3 = acc0;
#pragma unroll
  for (int kt = 0; kt < 4; ++kt) {
    const int ko = kt * 32 + quad * 8;
    short8 af = *(const short8*)&xs[(wv * 16 + l15) * PADK + ko];
    short8 b0 = *(const short8*)&ws[(l15) * PADK + ko];
    short8 b1 = *(const short8*)&ws[(16 + l15) * PADK + ko];
    short8 b2 = *(const short8*)&ws[(32 + l15) * PADK + ko];
    short8 b3 = *(const short8*)&ws[(48 + l15) * PADK + ko];
    acc0 = __builtin_amdgcn_mfma_f32_16x16x32_bf16(af, b0, acc0, 0, 0, 0);
    acc1 = __builtin_amdgcn_mfma_f32_16x16x32_bf16(af, b1, acc1, 0, 0, 0);
    acc2 = __builtin_amdgcn_mfma_f32_16x16x32_bf16(af, b2, acc2, 0, 0, 0);
    acc3 = __builtin_amdgcn_mfma_f32_16x16x32_bf16(af, b3, acc3, 0, 0, 0);
  }

  const float s0 = a1s_w[cb + l15],      s1 = a1s_w[cb + 16 + l15];
  const float s2 = a1s_w[cb + 32 + l15], s3 = a1s_w[cb + 48 + l15];
  const float d0 = a1d_w[cb + l15],      d1 = a1d_w[cb + 16 + l15];
  const float d2 = a1d_w[cb + 32 + l15], d3 = a1d_w[cb + 48 + l15];
#pragma unroll
  for (int r = 0; r < 4; ++r) {
    const int row = rb + wv * 16 + quad * 4 + r;
    const bool ok = row < n;
    if (ok) {
      size_t base = (size_t)row * F1 + cb;
      int pA = __builtin_amdgcn_cvt_pk_fp8_f32(acc0[r], acc1[r], 0, false);
      int pB = __builtin_amdgcn_cvt_pk_fp8_f32(acc2[r], acc3[r], 0, false);
      h1f8[base + l15]      = (unsigned char)(pA & 0xff);
      h1f8[base + 16 + l15] = (unsigned char)((pA >> 8) & 0xff);
      h1f8[base + 32 + l15] = (unsigned char)(pB & 0xff);
      h1f8[base + 48 + l15] = (unsigned char)((pB >> 8) & 0xff);
    }
    float ds = acc0[r] * s0 + acc1[r] * s1 + acc2[r] * s2 + acc3[r] * s3;
    float dd = acc0[r] * d0 + acc1[r] * d1 + acc2[r] * d2 + acc3[r] * d3;
#pragma unroll
    for (int m = 1; m <= 8; m <<= 1) {
      ds += __shfl_xor(ds, m, 64);
      dd += __shfl_xor(dd, m, 64);
    }
    if (ok && l15 == 0) {
      as1[(size_t)row * 4 + head] = ds;
      ad1[(size_t)row * 4 + head] = dd;
    }
  }
}

// ---- hist + rank capture ----
__global__ __launch_bounds__(256) void k_hist(const int* __restrict__ adj,
    int* __restrict__ cnt, int* __restrict__ rank, int E_, int n) {
  int e = blockIdx.x * 256 + threadIdx.x;
  int ET = E_ + n;
  if (e >= ET) return;
  int d = (e < E_) ? adj[E_ + e] : (e - E_);
  rank[e] = atomicAdd(&cnt[d], 1);
}

__global__ __launch_bounds__(256) void k_scan_local(const int* __restrict__ cnt,
    int* __restrict__ offs, int* __restrict__ bsum, int n) {
  __shared__ int wsums[4];
  const int tid = threadIdx.x;
  const int lane = tid & 63, w = tid >> 6;
  const int base = blockIdx.x * 1024;
  const int i0 = base + tid * 4;
  int v[4];
#pragma unroll
  for (int k = 0; k < 4; ++k) { int i = i0 + k; v[k] = (i < n) ? cnt[i] : 0; }
  int tsum = v[0] + v[1] + v[2] + v[3];
  int incl = tsum;
#pragma unroll
  for (int d = 1; d < 64; d <<= 1) {
    int t = __shfl_up(incl, (unsigned)d, 64);
    if (lane >= d) incl += t;
  }
  if (lane == 63) wsums[w] = incl;
  __syncthreads();
  int pre = 0;
  for (int k = 0; k < w; ++k) pre += wsums[k];
  int run = pre + incl - tsum;
#pragma unroll
  for (int k = 0; k < 4; ++k) { int i = i0 + k; if (i < n) offs[i] = run; run += v[k]; }
  if (tid == 255) bsum[blockIdx.x] = pre + incl;
}

__global__ void k_scan_bsum(int* __restrict__ bsum, int nb, int* __restrict__ offs_n) {
  int lane = threadIdx.x;   // 64 threads
  int carry = 0;
  for (int base = 0; base < nb; base += 64) {
    int i = base + lane;
    int v = (i < nb) ? bsum[i] : 0;
    int incl = v;
#pragma unroll
    for (int d = 1; d < 64; d <<= 1) {
      int t = __shfl_up(incl, (unsigned)d, 64);
      if (lane >= d) incl += t;
    }
    if (i < nb) bsum[i] = carry + incl - v;
    int tot = __shfl(incl, 63, 64);
    carry += tot;
  }
  if (lane == 0) *offs_n = carry;
}

__global__ __launch_bounds__(256) void k_scan_add(int* __restrict__ offs,
    const int* __restrict__ bsum, int n) {
  int i = blockIdx.x * 256 + threadIdx.x;
  if (i < n) offs[i] += bsum[i >> 10];
}

// -------- scatter, atomic-free; rec = {src, w01, w23, dst}; nt loads for streams --------
__global__ __launch_bounds__(256) void k_scatter(const int* __restrict__ adj,
    const int* __restrict__ rank, const int* __restrict__ offs,
    const float* __restrict__ as1, const float* __restrict__ ad1,
    uint4* __restrict__ csr, int E_, int n, int binw) {
  const int bin = blockIdx.x & 7;
  const int chunk = blockIdx.x >> 3;
  const int e = chunk * 256 + threadIdx.x;
  const int ET = E_ + n;
  if (e >= ET) return;
  int d = (e < E_) ? __builtin_nontemporal_load(adj + E_ + e) : (e - E_);
  const int lo = bin * binw;
  if (d < lo || d >= lo + binw) return;   // not my bin
  int s = (e < E_) ? __builtin_nontemporal_load(adj + e) : d;
  int pos = offs[d] + __builtin_nontemporal_load(rank + e);
  const float4 qs = *(const float4*)(as1 + (size_t)s * 4);
  const float4 qd = *(const float4*)(ad1 + (size_t)d * 4);
  float ev, w0, w1, w2, w3;
  ev = qs.x + qd.x; ev = (ev >= 0.f) ? ev : NEG * ev; w0 = __expf(ev);
  ev = qs.y + qd.y; ev = (ev >= 0.f) ? ev : NEG * ev; w1 = __expf(ev);
  ev = qs.z + qd.z; ev = (ev >= 0.f) ? ev : NEG * ev; w2 = __expf(ev);
  ev = qs.w + qd.w; ev = (ev >= 0.f) ? ev : NEG * ev; w3 = __expf(ev);
  uint4 rec;
  rec.x = (unsigned)s;
  rec.y = (unsigned)f2b(w0) | ((unsigned)f2b(w1) << 16);
  rec.z = (unsigned)f2b(w2) | ((unsigned)f2b(w3) << 16);
  rec.w = (unsigned)d;
  csr[pos] = rec;
}

// ------- fused GAT layer 1 (fp8 gather, half-wave edge pairing) -------
// Half-wave owns one edge; lane l (0..31) covers feats 8l..8l+7 (one uint2 of fp8),
// head h = l>>3. Serial trips halve vs R11's full-wave loop; 4 gathers in flight.
__global__ __launch_bounds__(256) void k_agg1(const unsigned char* __restrict__ h1f8,
    const int* __restrict__ offs, const uint4* __restrict__ csr,
    const float* __restrict__ b1, unsigned short* __restrict__ relu1b, int n) {
  int node = blockIdx.x * 4 + (threadIdx.x >> 6);
  int lane = threadIdx.x & 63;
  if (node >= n) return;
  const int sub = lane >> 5;       // which edge of the pair
  const int l = lane & 31;         // feature octet
  const int h = l >> 3;            // head
  const bool hHi = (h & 2) != 0, hOdd = (h & 1) != 0;
  const int j0 = offs[node], j1 = offs[node + 1];
  float a0=0.f,a1=0.f,a2=0.f,a3=0.f,a4=0.f,a5=0.f,a6=0.f,a7=0.f,den=0.f;
  int j = j0;
  for (; j + 4 <= j1; j += 4) {
    const uint4 rA = csr[j + sub];
    const uint4 rB = csr[j + 2 + sub];
    const uint2 uA = ((const uint2*)(h1f8 + (size_t)rA.x * F1))[l];
    const uint2 uB = ((const uint2*)(h1f8 + (size_t)rB.x * F1))[l];
    unsigned ws; float w;
    v2f p0, p1, p2, p3;
    ws = hHi ? rA.z : rA.y; w = hOdd ? b2fh(ws) : b2fl(ws);
    p0 = __builtin_amdgcn_cvt_pk_f32_fp8(uA.x, false);
    p1 = __builtin_amdgcn_cvt_pk_f32_fp8(uA.x, true);
    p2 = __builtin_amdgcn_cvt_pk_f32_fp8(uA.y, false);
    p3 = __builtin_amdgcn_cvt_pk_f32_fp8(uA.y, true);
    den += w;
    a0 += w * p0.x; a1 += w * p0.y; a2 += w * p1.x; a3 += w * p1.y;
    a4 += w * p2.x; a5 += w * p2.y; a6 += w * p3.x; a7 += w * p3.y;
    ws = hHi ? rB.z : rB.y; w = hOdd ? b2fh(ws) : b2fl(ws);
    p0 = __builtin_amdgcn_cvt_pk_f32_fp8(uB.x, false);
    p1 = __builtin_amdgcn_cvt_pk_f32_fp8(uB.x, true);
    p2 = __builtin_amdgcn_cvt_pk_f32_fp8(uB.y, false);
    p3 = __builtin_amdgcn_cvt_pk_f32_fp8(uB.y, true);
    den += w;
    a0 += w * p0.x; a1 += w * p0.y; a2 += w * p1.x; a3 += w * p1.y;
    a4 += w * p2.x; a5 += w * p2.y; a6 += w * p3.x; a7 += w * p3.y;
  }
  for (; j < j1; j += 2) {
    const int idx = j + sub;
    const bool valid = idx < j1;
    const uint4 r = csr[valid ? idx : (j1 - 1)];
    const uint2 u = ((const uint2*)(h1f8 + (size_t)r.x * F1))[l];
    unsigned ws = hHi ? r.z : r.y;
    float w = hOdd ? b2fh(ws) : b2fl(ws);
    if (!valid) w = 0.f;
    v2f p0 = __builtin_amdgcn_cvt_pk_f32_fp8(u.x, false);
    v2f p1 = __builtin_amdgcn_cvt_pk_f32_fp8(u.x, true);
    v2f p2 = __builtin_amdgcn_cvt_pk_f32_fp8(u.y, false);
    v2f p3 = __builtin_amdgcn_cvt_pk_f32_fp8(u.y, true);
    den += w;
    a0 += w * p0.x; a1 += w * p0.y; a2 += w * p1.x; a3 += w * p1.y;
    a4 += w * p2.x; a5 += w * p2.y; a6 += w * p3.x; a7 += w * p3.y;
  }
  // combine the two half-waves (lane pairs l, l^32 hold same features)
  den += __shfl_xor(den, 32, 64);
  a0 += __shfl_xor(a0, 32, 64); a1 += __shfl_xor(a1, 32, 64);
  a2 += __shfl_xor(a2, 32, 64); a3 += __shfl_xor(a3, 32, 64);
  a4 += __shfl_xor(a4, 32, 64); a5 += __shfl_xor(a5, 32, 64);
  a6 += __shfl_xor(a6, 32, 64); a7 += __shfl_xor(a7, 32, 64);
  if (sub == 0) {
    const float inv = 1.0f / den;
    const float4 bb0 = ((const float4*)b1)[2 * l];
    const float4 bb1 = ((const float4*)b1)[2 * l + 1];
    ushort4 r0, r1;
    r0.x = f2b(fmaxf(a0 * inv + bb0.x, 0.f));
    r0.y = f2b(fmaxf(a1 * inv + bb0.y, 0.f));
    r0.z = f2b(fmaxf(a2 * inv + bb0.z, 0.f));
    r0.w = f2b(fmaxf(a3 * inv + bb0.w, 0.f));
    r1.x = f2b(fmaxf(a4 * inv + bb1.x, 0.f));
    r1.y = f2b(fmaxf(a5 * inv + bb1.y, 0.f));
    r1.z = f2b(fmaxf(a6 * inv + bb1.z, 0.f));
    r1.w = f2b(fmaxf(a7 * inv + bb1.w, 0.f));
    *(ushort4*)&relu1b[(size_t)node * F1 + 8 * l] = r0;
    *(ushort4*)&relu1b[(size_t)node * F1 + 8 * l + 4] = r1;
  }
}

// ---------------- GEMM2 (register-tiled; bf16 relu1 input) ----------------
__global__ __launch_bounds__(256) void k_gemm2(const unsigned short* __restrict__ relu1b,
    const float* __restrict__ W2, const float* __restrict__ a2s_w,
    const float* __restrict__ a2d_w, unsigned short* __restrict__ h2b,
    float* __restrict__ as2, float* __restrict__ ad2, int n) {
  __shared__ float w2s[F1 * OUT_DIM];  // 32 KB
  __shared__ float xs[32][72];         // [k][row], 2-way bank alias = free
  const int tid = threadIdx.x;
  const int rb = blockIdx.x * 64;
  for (int i = tid; i < F1 * OUT_DIM; i += 256) w2s[i] = W2[i];
  const int rx = tid >> 3;       // 0..31 -> rows rx, rx+32
  const int cq = tid & 7;        // 0..7  -> cols 4cq..4cq+3
  float accA[4] = {0.f, 0.f, 0.f, 0.f};
  float accB[4] = {0.f, 0.f, 0.f, 0.f};
  for (int kb = 0; kb < F1; kb += 32) {
    __syncthreads();
#pragma unroll
    for (int i = 0; i < 2; ++i) {
      int idx = tid + i * 256;            // 0..511
      int r = idx >> 3, c4 = idx & 7;     // row 0..63, uint2 group (4 k-vals)
      int row = rb + r;
      uint2 u = make_uint2(0u, 0u);
      if (row < n) u = *(const uint2*)&relu1b[(size_t)row * F1 + kb + c4 * 4];
      xs[c4 * 4 + 0][r] = b2fl(u.x); xs[c4 * 4 + 1][r] = b2fh(u.x);
      xs[c4 * 4 + 2][r] = b2fl(u.y); xs[c4 * 4 + 3][r] = b2fh(u.y);
    }
    __syncthreads();
#pragma unroll
    for (int kk = 0; kk < 32; ++kk) {
      const float xa = xs[kk][rx];
      const float xb = xs[kk][rx + 32];
      const float4 wv = *(const float4*)&w2s[(kb + kk) * OUT_DIM + 4 * cq];
      accA[0] += xa * wv.x; accA[1] += xa * wv.y; accA[2] += xa * wv.z; accA[3] += xa * wv.w;
      accB[0] += xb * wv.x; accB[1] += xb * wv.y; accB[2] += xb * wv.z; accB[3] += xb * wv.w;
    }
  }
  const float4 sv = *(const float4*)&a2s_w[4 * cq];
  const float4 dv = *(const float4*)&a2d_w[4 * cq];
  const int rA = rb + rx, rB = rb + rx + 32;
  if (rA < n) {
    ushort4 v; v.x = f2b(accA[0]); v.y = f2b(accA[1]); v.z = f2b(accA[2]); v.w = f2b(accA[3]);
    *(ushort4*)&h2b[(size_t)rA * OUT_DIM + 4 * cq] = v;
  }
  if (rB < n) {
    ushort4 v; v.x = f2b(accB[0]); v.y = f2b(accB[1]); v.z = f2b(accB[2]); v.w = f2b(accB[3]);
    *(ushort4*)&h2b[(size_t)rB * OUT_DIM + 4 * cq] = v;
  }
  float ssA = accA[0] * sv.x + accA[1] * sv.y + accA[2] * sv.z + accA[3] * sv.w;
  float sdA = accA[0] * dv.x + accA[1] * dv.y + accA[2] * dv.z + accA[3] * dv.w;
  float ssB = accB[0] * sv.x + accB[1] * sv.y + accB[2] * sv.z + accB[3] * sv.w;
  float sdB = accB[0] * dv.x + accB[1] * dv.y + accB[2] * dv.z + accB[3] * dv.w;
#pragma unroll
  for (int m = 1; m <= 4; m <<= 1) {
    ssA += __shfl_xor(ssA, m, 64);
    sdA += __shfl_xor(sdA, m, 64);
    ssB += __shfl_xor(ssB, m, 64);
    sdB += __shfl_xor(sdB, m, 64);
  }
  if (cq == 0) {
    if (rA < n) { as2[rA] = ssA; ad2[rA] = sdA; }
    if (rB < n) { as2[rB] = ssB; ad2[rB] = sdB; }
  }
}

// ---- w2 precompute: one thread per edge; coalesced record read, cached as2/ad2 ----
// (hoists the exp that k_agg2 computed with 16x lane redundancy in-loop)
// NOTE: nontemporal builtin can't take uint4* — use scalar loads of the two
// fields we need (src at 4e, dst at 4e+3).
__global__ __launch_bounds__(256) void k_w2(const unsigned* __restrict__ csr_i,
    const float* __restrict__ as2, const float* __restrict__ ad2,
    float* __restrict__ w2, int tot) {
  int e = blockIdx.x * 256 + threadIdx.x;
  if (e >= tot) return;
  unsigned s = __builtin_nontemporal_load(csr_i + 4 * (size_t)e);
  unsigned d = __builtin_nontemporal_load(csr_i + 4 * (size_t)e + 3);
  float ev = as2[s] + ad2[d];
  ev = (ev >= 0.f) ? ev : NEG * ev;
  w2[e] = __expf(ev);
}

// -------- fused GAT layer 2 (bf16 gather, quarter-wave, precomputed w2) --------
__global__ __launch_bounds__(256) void k_agg2(const unsigned short* __restrict__ h2b,
    const float* __restrict__ w2, const int* __restrict__ offs,
    const uint4* __restrict__ csr, const float* __restrict__ b2,
    const float* __restrict__ linW, float* __restrict__ score, int n) {
  int node = blockIdx.x * 4 + (threadIdx.x >> 6);
  int lane = threadIdx.x & 63;
  if (node >= n) return;
  const int sub = lane >> 4;
  const int p = lane & 15;
  const int j0 = offs[node], j1 = offs[node + 1];
  const int* csr_i = (const int*)csr;   // record stride 4 ints; src at 4*j
  float acc0 = 0.f, acc1 = 0.f, den = 0.f;
  int jj = j0;
  for (; jj + 8 <= j1; jj += 8) {
    const int iA = jj + sub, iB = jj + 4 + sub;
    const int sA = csr_i[4 * iA];
    const int sB = csr_i[4 * iB];
    const float wA = w2[iA], wB = w2[iB];
    const unsigned uA = ((const unsigned*)(h2b + (size_t)sA * OUT_DIM))[p];
    const unsigned uB = ((const unsigned*)(h2b + (size_t)sB * OUT_DIM))[p];
    den += wA; acc0 += wA * b2fl(uA); acc1 += wA * b2fh(uA);
    den += wB; acc0 += wB * b2fl(uB); acc1 += wB * b2fh(uB);
  }
  for (; jj < j1; jj += 4) {
    const int idx = jj + sub;
    const bool valid = idx < j1;
    const int ridx = valid ? idx : (j1 - 1);
    const int s = csr_i[4 * ridx];
    const float w = valid ? w2[ridx] : 0.f;
    const unsigned u = ((const unsigned*)(h2b + (size_t)s * OUT_DIM))[p];
    den += w; acc0 += w * b2fl(u); acc1 += w * b2fh(u);
  }
  den  += __shfl_xor(den, 16, 64);  den  += __shfl_xor(den, 32, 64);
  acc0 += __shfl_xor(acc0, 16, 64); acc0 += __shfl_xor(acc0, 32, 64);
  acc1 += __shfl_xor(acc1, 16, 64); acc1 += __shfl_xor(acc1, 32, 64);
  const float inv = 1.0f / den;
  float o0 = acc0 * inv + b2[2 * p];
  float o1 = acc1 * inv + b2[2 * p + 1];
  float m = fmaxf(o0, o1);
#pragma unroll
  for (int mm = 1; mm <= 8; mm <<= 1) m = fmaxf(m, __shfl_xor(m, mm, 64));
  float ssum = __expf(o0 - m) + __expf(o1 - m);
#pragma unroll
  for (int mm = 1; mm <= 8; mm <<= 1) ssum += __shfl_xor(ssum, mm, 64);
  const float lse = m + __logf(ssum);
  float sc = (o0 - lse) * linW[2 * p] + (o1 - lse) * linW[2 * p + 1];
#pragma unroll
  for (int mm = 1; mm <= 8; mm <<= 1) sc += __shfl_xor(sc, mm, 64);
  if (lane == 0) score[node] = sc;
}

// -------- pooling: LDS per-graph partials, few global atomics per block --------
__global__ __launch_bounds__(256) void k_pool(const float* __restrict__ score,
    const int* __restrict__ batch, float* __restrict__ gsum,
    float* __restrict__ gcnt, int n) {
  __shared__ float ps[64];
  __shared__ float pc[64];
  const int tid = threadIdx.x;
  if (tid < 64) { ps[tid] = 0.f; pc[tid] = 0.f; }
  __syncthreads();
  int i = blockIdx.x * 256 + tid;
  if (i < n) {
    int g = batch[i];
    atomicAdd(&ps[g], score[i]);
    atomicAdd(&pc[g], 1.0f);
  }
  __syncthreads();
  if (tid < 64 && pc[tid] != 0.f) {
    atomicAdd(&gsum[tid], ps[tid]);
    atomicAdd(&gcnt[tid], pc[tid]);
  }
}

__global__ void k_final(const float* __restrict__ gsum, const float* __restrict__ gcnt,
                        const float* __restrict__ linb, float* __restrict__ out, int g_) {
  int g = threadIdx.x;
  if (g < g_) out[g] = gsum[g] / fmaxf(gcnt[g], 1.0f) + linb[0];
}

extern "C" void kernel_launch(void* const* d_in, const int* in_sizes, int n_in,
                              void* d_out, int out_size, void* d_ws, size_t ws_size,
                              hipStream_t stream) {
  const float* x    = (const float*)d_in[0];
  const int*   adj  = (const int*)d_in[1];
  const int*   batch= (const int*)d_in[2];
  const float* W1   = (const float*)d_in[3];
  const float* a1s  = (const float*)d_in[4];
  const float* a1d  = (const float*)d_in[5];
  const float* b1   = (const float*)d_in[6];
  const float* W2   = (const float*)d_in[7];
  const float* a2s  = (const float*)d_in[8];
  const float* a2d  = (const float*)d_in[9];
  const float* b2   = (const float*)d_in[10];
  const float* linW = (const float*)d_in[11];
  const float* linb = (const float*)d_in[12];

  const int N = in_sizes[0] / IN_DIM;
  const int E = in_sizes[1] / 2;
  const int ET = E + N;
  const int G = out_size;   // 64
  const int NB = (N + 1023) / 1024;
  const int BINW = (N + 7) / 8;

  char* wsb = (char*)d_ws;
  size_t off = 0;
  auto take = [&](size_t bytes) -> char* {
    char* p = wsb + off;
    off += (bytes + 255) & ~(size_t)255;
    return p;
  };
  unsigned char* h1f8  = (unsigned char*)take((size_t)N * F1);
  unsigned short* relu1b= (unsigned short*)take((size_t)N * F1 * 2);
  float* as1    = (float*)take((size_t)N * 4 * 4);
  float* ad1    = (float*)take((size_t)N * 4 * 4);
  unsigned short* h2b = (unsigned short*)take((size_t)N * OUT_DIM * 2);
  float* as2v   = (float*)take((size_t)N * 4);
  float* ad2v   = (float*)take((size_t)N * 4);
  float* score  = (float*)take((size_t)N * 4);
  int*   cnt    = (int*)take((size_t)N * 4);
  int*   offs   = (int*)take((size_t)(N + 1) * 4);
  int*   rank   = (int*)take((size_t)ET * 4);
  uint4* csr    = (uint4*)take((size_t)ET * 16);
  float* w2v    = (float*)take((size_t)ET * 4);
  int*   bsum   = (int*)take((size_t)(NB + 1) * 4);
  float* gsum   = (float*)take((size_t)G * 4);
  float* gcnt   = (float*)take((size_t)G * 4);
  unsigned short* W1t = (unsigned short*)take((size_t)IN_DIM * F1 * 2);
  (void)ws_size; (void)n_in;

  hipMemsetAsync(cnt, 0, (size_t)N * 4, stream);
  hipMemsetAsync(gsum, 0, (size_t)G * 4, stream);
  hipMemsetAsync(gcnt, 0, (size_t)G * 4, stream);

  dim3 b256(256);
  k_prep<<<dim3((IN_DIM * F1) / 256), b256, 0, stream>>>(W1, W1t);
  k_gemm1<<<dim3((N + 63) / 64, F1 / 64), b256, 0, stream>>>(x, W1t, a1s, a1d, h1f8, as1, ad1, N);
  k_hist<<<dim3((ET + 255) / 256), b256, 0, stream>>>(adj, cnt, rank, E, N);
  k_scan_local<<<dim3(NB), b256, 0, stream>>>(cnt, offs, bsum, N);
  k_scan_bsum<<<1, 64, 0, stream>>>(bsum, NB, offs + N);
  k_scan_add<<<dim3((N + 255) / 256), b256, 0, stream>>>(offs, bsum, N);
  k_scatter<<<dim3(((ET + 255) / 256) * 8), b256, 0, stream>>>(adj, rank, offs, as1, ad1, csr, E, N, BINW);
  k_agg1<<<dim3((N + 3) / 4), b256, 0, stream>>>(h1f8, offs, csr, b1, relu1b, N);
  k_gemm2<<<dim3((N + 63) / 64), b256, 0, stream>>>(relu1b, W2, a2s, a2d, h2b, as2v, ad2v, N);
  k_w2<<<dim3((ET + 255) / 256), b256, 0, stream>>>((const unsigned*)csr, as2v, ad2v, w2v, ET);
  k_agg2<<<dim3((N + 3) / 4), b256, 0, stream>>>(h2b, w2v, offs, csr, b2, linW, score, N);
  k_pool<<<dim3((N + 255) / 256), b256, 0, stream>>>(score, batch, gsum, gcnt, N);
  k_final<<<1, 64, 0, stream>>>(gsum, gcnt, linb, (float*)d_out, G);
}

// Round 14
// 302.231 us; speedup vs baseline: 1.0763x; 1.0763x over previous
//
#include <hip/hip_runtime.h>

#define IN_DIM 128
#define F1 256      // HEADS*HID = 4*64
#define HID 64
#define OUT_DIM 32
#define NEG 0.2f
#define PADK 136    // LDS row pitch in bf16 elems (128 + 8): frag reads 2-way alias = free

typedef __attribute__((ext_vector_type(8))) short short8;
typedef __attribute__((ext_vector_type(4))) float v4f;
typedef __attribute__((ext_vector_type(2))) float v2f;

// ---- bf16 helpers ----
__device__ __forceinline__ float b2fl(unsigned u) {
  union { unsigned i; float f; } c; c.i = u << 16; return c.f;
}
__device__ __forceinline__ float b2fh(unsigned u) {
  union { unsigned i; float f; } c; c.i = u & 0xffff0000u; return c.f;
}
__device__ __forceinline__ unsigned short f2b(float f) {
  union { float f; unsigned i; } c; c.f = f;
  unsigned r = c.i + 0x7fffu + ((c.i >> 16) & 1u);   // RNE
  return (unsigned short)(r >> 16);
}

// ---- prep: W1t[n][k] bf16 = transpose of W1[k][n] fp32 (one-time, 32K elems) ----
__global__ __launch_bounds__(256) void k_prep(const float* __restrict__ W1,
    unsigned short* __restrict__ W1t) {
  int idx = blockIdx.x * 256 + threadIdx.x;   // 0..32767
  int nn = idx >> 7, k = idx & 127;
  W1t[idx] = f2b(W1[(size_t)k * F1 + nn]);
}

// ------- GEMM1 via MFMA: h1f8[N,256](fp8 e4m3) = bf16(x)[N,128] @ W1[128,256] -------
__global__ __launch_bounds__(256) void k_gemm1(const float* __restrict__ x,
    const unsigned short* __restrict__ W1t,
    const float* __restrict__ a1s_w, const float* __restrict__ a1d_w,
    unsigned char* __restrict__ h1f8, float* __restrict__ as1,
    float* __restrict__ ad1, int n) {
  __shared__ unsigned short xs[64 * PADK];   // 17.4 KB
  __shared__ unsigned short ws[64 * PADK];   // 17.4 KB
  const int tid = threadIdx.x;
  const int rb = blockIdx.x * 64;
  const int head = blockIdx.y;
  const int cb = head * 64;

#pragma unroll
  for (int i = 0; i < 8; ++i) {
    int idx = tid + i * 256;
    int row = idx >> 5, c4 = idx & 31;
    float4 v = make_float4(0.f, 0.f, 0.f, 0.f);
    if (rb + row < n) v = *(const float4*)&x[(size_t)(rb + row) * IN_DIM + c4 * 4];
    ushort4 b; b.x = f2b(v.x); b.y = f2b(v.y); b.z = f2b(v.z); b.w = f2b(v.w);
    *(ushort4*)&xs[row * PADK + c4 * 4] = b;
  }
#pragma unroll
  for (int i = 0; i < 4; ++i) {
    int idx = tid + i * 256;
    int row = idx >> 4, c = idx & 15;
    *(uint4*)&ws[row * PADK + c * 8] =
        *(const uint4*)&W1t[(size_t)(cb + row) * IN_DIM + c * 8];
  }
  __syncthreads();

  const int wv = tid >> 6;
  const int lane = tid & 63;
  const int l15 = lane & 15, quad = lane >> 4;
  v4f acc0 = {0.f, 0.f, 0.f, 0.f}, acc1 = acc0, acc2 = acc0, acc3 = acc0;
#pragma unroll
  for (int kt = 0; kt < 4; ++kt) {
    const int ko = kt * 32 + quad * 8;
    short8 af = *(const short8*)&xs[(wv * 16 + l15) * PADK + ko];
    short8 b0 = *(const short8*)&ws[(l15) * PADK + ko];
    short8 b1 = *(const short8*)&ws[(16 + l15) * PADK + ko];
    short8 b2 = *(const short8*)&ws[(32 + l15) * PADK + ko];
    short8 b3 = *(const short8*)&ws[(48 + l15) * PADK + ko];
    acc0 = __builtin_amdgcn_mfma_f32_16x16x32_bf16(af, b0, acc0, 0, 0, 0);
    acc1 = __builtin_amdgcn_mfma_f32_16x16x32_bf16(af, b1, acc1, 0, 0, 0);
    acc2 = __builtin_amdgcn_mfma_f32_16x16x32_bf16(af, b2, acc2, 0, 0, 0);
    acc3 = __builtin_amdgcn_mfma_f32_16x16x32_bf16(af, b3, acc3, 0, 0, 0);
  }

  const float s0 = a1s_w[cb + l15],      s1 = a1s_w[cb + 16 + l15];
  const float s2 = a1s_w[cb + 32 + l15], s3 = a1s_w[cb + 48 + l15];
  const float d0 = a1d_w[cb + l15],      d1 = a1d_w[cb + 16 + l15];
  const float d2 = a1d_w[cb + 32 + l15], d3 = a1d_w[cb + 48 + l15];
#pragma unroll
  for (int r = 0; r < 4; ++r) {
    const int row = rb + wv * 16 + quad * 4 + r;
    const bool ok = row < n;
    if (ok) {
      size_t base = (size_t)row * F1 + cb;
      int pA = __builtin_amdgcn_cvt_pk_fp8_f32(acc0[r], acc1[r], 0, false);
      int pB = __builtin_amdgcn_cvt_pk_fp8_f32(acc2[r], acc3[r], 0, false);
      h1f8[base + l15]      = (unsigned char)(pA & 0xff);
      h1f8[base + 16 + l15] = (unsigned char)((pA >> 8) & 0xff);
      h1f8[base + 32 + l15] = (unsigned char)(pB & 0xff);
      h1f8[base + 48 + l15] = (unsigned char)((pB >> 8) & 0xff);
    }
    float ds = acc0[r] * s0 + acc1[r] * s1 + acc2[r] * s2 + acc3[r] * s3;
    float dd = acc0[r] * d0 + acc1[r] * d1 + acc2[r] * d2 + acc3[r] * d3;
#pragma unroll
    for (int m = 1; m <= 8; m <<= 1) {
      ds += __shfl_xor(ds, m, 64);
      dd += __shfl_xor(dd, m, 64);
    }
    if (ok && l15 == 0) {
      as1[(size_t)row * 4 + head] = ds;
      ad1[(size_t)row * 4 + head] = dd;
    }
  }
}

// ---- hist + rank capture ----
__global__ __launch_bounds__(256) void k_hist(const int* __restrict__ adj,
    int* __restrict__ cnt, int* __restrict__ rank, int E_, int n) {
  int e = blockIdx.x * 256 + threadIdx.x;
  int ET = E_ + n;
  if (e >= ET) return;
  int d = (e < E_) ? adj[E_ + e] : (e - E_);
  rank[e] = atomicAdd(&cnt[d], 1);
}

__global__ __launch_bounds__(256) void k_scan_local(const int* __restrict__ cnt,
    int* __restrict__ offs, int* __restrict__ bsum, int n) {
  __shared__ int wsums[4];
  const int tid = threadIdx.x;
  const int lane = tid & 63, w = tid >> 6;
  const int base = blockIdx.x * 1024;
  const int i0 = base + tid * 4;
  int v[4];
#pragma unroll
  for (int k = 0; k < 4; ++k) { int i = i0 + k; v[k] = (i < n) ? cnt[i] : 0; }
  int tsum = v[0] + v[1] + v[2] + v[3];
  int incl = tsum;
#pragma unroll
  for (int d = 1; d < 64; d <<= 1) {
    int t = __shfl_up(incl, (unsigned)d, 64);
    if (lane >= d) incl += t;
  }
  if (lane == 63) wsums[w] = incl;
  __syncthreads();
  int pre = 0;
  for (int k = 0; k < w; ++k) pre += wsums[k];
  int run = pre + incl - tsum;
#pragma unroll
  for (int k = 0; k < 4; ++k) { int i = i0 + k; if (i < n) offs[i] = run; run += v[k]; }
  if (tid == 255) bsum[blockIdx.x] = pre + incl;
}

__global__ void k_scan_bsum(int* __restrict__ bsum, int nb, int* __restrict__ offs_n) {
  int lane = threadIdx.x;   // 64 threads
  int carry = 0;
  for (int base = 0; base < nb; base += 64) {
    int i = base + lane;
    int v = (i < nb) ? bsum[i] : 0;
    int incl = v;
#pragma unroll
    for (int d = 1; d < 64; d <<= 1) {
      int t = __shfl_up(incl, (unsigned)d, 64);
      if (lane >= d) incl += t;
    }
    if (i < nb) bsum[i] = carry + incl - v;
    int tot = __shfl(incl, 63, 64);
    carry += tot;
  }
  if (lane == 0) *offs_n = carry;
}

__global__ __launch_bounds__(256) void k_scan_add(int* __restrict__ offs,
    const int* __restrict__ bsum, int n) {
  int i = blockIdx.x * 256 + threadIdx.x;
  if (i < n) offs[i] += bsum[i >> 10];
}

// -------- scatter, atomic-free; rec = {src, w01, w23, dst} --------
// R13 ERRATUM: nontemporal loads here REGRESSED 32->50 us (they bypass L2 fill,
// so the 8 bin passes re-read adj/rank from HBM at ~900cyc instead of L2 ~200cyc).
// Regular cached loads restored; the 8-bin XCD swizzle stays (write locality).
__global__ __launch_bounds__(256) void k_scatter(const int* __restrict__ adj,
    const int* __restrict__ rank, const int* __restrict__ offs,
    const float* __restrict__ as1, const float* __restrict__ ad1,
    uint4* __restrict__ csr, int E_, int n, int binw) {
  const int bin = blockIdx.x & 7;
  const int chunk = blockIdx.x >> 3;
  const int e = chunk * 256 + threadIdx.x;
  const int ET = E_ + n;
  if (e >= ET) return;
  int d = (e < E_) ? adj[E_ + e] : (e - E_);
  const int lo = bin * binw;
  if (d < lo || d >= lo + binw) return;   // not my bin
  int s = (e < E_) ? adj[e] : d;
  int pos = offs[d] + rank[e];
  const float4 qs = *(const float4*)(as1 + (size_t)s * 4);
  const float4 qd = *(const float4*)(ad1 + (size_t)d * 4);
  float ev, w0, w1, w2, w3;
  ev = qs.x + qd.x; ev = (ev >= 0.f) ? ev : NEG * ev; w0 = __expf(ev);
  ev = qs.y + qd.y; ev = (ev >= 0.f) ? ev : NEG * ev; w1 = __expf(ev);
  ev = qs.z + qd.z; ev = (ev >= 0.f) ? ev : NEG * ev; w2 = __expf(ev);
  ev = qs.w + qd.w; ev = (ev >= 0.f) ? ev : NEG * ev; w3 = __expf(ev);
  uint4 rec;
  rec.x = (unsigned)s;
  rec.y = (unsigned)f2b(w0) | ((unsigned)f2b(w1) << 16);
  rec.z = (unsigned)f2b(w2) | ((unsigned)f2b(w3) << 16);
  rec.w = (unsigned)d;
  csr[pos] = rec;
}

// ------- fused GAT layer 1 (fp8 gather, half-wave edge pairing) -------
__global__ __launch_bounds__(256) void k_agg1(const unsigned char* __restrict__ h1f8,
    const int* __restrict__ offs, const uint4* __restrict__ csr,
    const float* __restrict__ b1, unsigned short* __restrict__ relu1b, int n) {
  int node = blockIdx.x * 4 + (threadIdx.x >> 6);
  int lane = threadIdx.x & 63;
  if (node >= n) return;
  const int sub = lane >> 5;       // which edge of the pair
  const int l = lane & 31;         // feature octet
  const int h = l >> 3;            // head
  const bool hHi = (h & 2) != 0, hOdd = (h & 1) != 0;
  const int j0 = offs[node], j1 = offs[node + 1];
  float a0=0.f,a1=0.f,a2=0.f,a3=0.f,a4=0.f,a5=0.f,a6=0.f,a7=0.f,den=0.f;
  int j = j0;
  for (; j + 4 <= j1; j += 4) {
    const uint4 rA = csr[j + sub];
    const uint4 rB = csr[j + 2 + sub];
    const uint2 uA = ((const uint2*)(h1f8 + (size_t)rA.x * F1))[l];
    const uint2 uB = ((const uint2*)(h1f8 + (size_t)rB.x * F1))[l];
    unsigned ws; float w;
    v2f p0, p1, p2, p3;
    ws = hHi ? rA.z : rA.y; w = hOdd ? b2fh(ws) : b2fl(ws);
    p0 = __builtin_amdgcn_cvt_pk_f32_fp8(uA.x, false);
    p1 = __builtin_amdgcn_cvt_pk_f32_fp8(uA.x, true);
    p2 = __builtin_amdgcn_cvt_pk_f32_fp8(uA.y, false);
    p3 = __builtin_amdgcn_cvt_pk_f32_fp8(uA.y, true);
    den += w;
    a0 += w * p0.x; a1 += w * p0.y; a2 += w * p1.x; a3 += w * p1.y;
    a4 += w * p2.x; a5 += w * p2.y; a6 += w * p3.x; a7 += w * p3.y;
    ws = hHi ? rB.z : rB.y; w = hOdd ? b2fh(ws) : b2fl(ws);
    p0 = __builtin_amdgcn_cvt_pk_f32_fp8(uB.x, false);
    p1 = __builtin_amdgcn_cvt_pk_f32_fp8(uB.x, true);
    p2 = __builtin_amdgcn_cvt_pk_f32_fp8(uB.y, false);
    p3 = __builtin_amdgcn_cvt_pk_f32_fp8(uB.y, true);
    den += w;
    a0 += w * p0.x; a1 += w * p0.y; a2 += w * p1.x; a3 += w * p1.y;
    a4 += w * p2.x; a5 += w * p2.y; a6 += w * p3.x; a7 += w * p3.y;
  }
  for (; j < j1; j += 2) {
    const int idx = j + sub;
    const bool valid = idx < j1;
    const uint4 r = csr[valid ? idx : (j1 - 1)];
    const uint2 u = ((const uint2*)(h1f8 + (size_t)r.x * F1))[l];
    unsigned ws = hHi ? r.z : r.y;
    float w = hOdd ? b2fh(ws) : b2fl(ws);
    if (!valid) w = 0.f;
    v2f p0 = __builtin_amdgcn_cvt_pk_f32_fp8(u.x, false);
    v2f p1 = __builtin_amdgcn_cvt_pk_f32_fp8(u.x, true);
    v2f p2 = __builtin_amdgcn_cvt_pk_f32_fp8(u.y, false);
    v2f p3 = __builtin_amdgcn_cvt_pk_f32_fp8(u.y, true);
    den += w;
    a0 += w * p0.x; a1 += w * p0.y; a2 += w * p1.x; a3 += w * p1.y;
    a4 += w * p2.x; a5 += w * p2.y; a6 += w * p3.x; a7 += w * p3.y;
  }
  den += __shfl_xor(den, 32, 64);
  a0 += __shfl_xor(a0, 32, 64); a1 += __shfl_xor(a1, 32, 64);
  a2 += __shfl_xor(a2, 32, 64); a3 += __shfl_xor(a3, 32, 64);
  a4 += __shfl_xor(a4, 32, 64); a5 += __shfl_xor(a5, 32, 64);
  a6 += __shfl_xor(a6, 32, 64); a7 += __shfl_xor(a7, 32, 64);
  if (sub == 0) {
    const float inv = 1.0f / den;
    const float4 bb0 = ((const float4*)b1)[2 * l];
    const float4 bb1 = ((const float4*)b1)[2 * l + 1];
    ushort4 r0, r1;
    r0.x = f2b(fmaxf(a0 * inv + bb0.x, 0.f));
    r0.y = f2b(fmaxf(a1 * inv + bb0.y, 0.f));
    r0.z = f2b(fmaxf(a2 * inv + bb0.z, 0.f));
    r0.w = f2b(fmaxf(a3 * inv + bb0.w, 0.f));
    r1.x = f2b(fmaxf(a4 * inv + bb1.x, 0.f));
    r1.y = f2b(fmaxf(a5 * inv + bb1.y, 0.f));
    r1.z = f2b(fmaxf(a6 * inv + bb1.z, 0.f));
    r1.w = f2b(fmaxf(a7 * inv + bb1.w, 0.f));
    *(ushort4*)&relu1b[(size_t)node * F1 + 8 * l] = r0;
    *(ushort4*)&relu1b[(size_t)node * F1 + 8 * l + 4] = r1;
  }
}

// ---------------- GEMM2 (register-tiled; bf16 relu1 input) ----------------
__global__ __launch_bounds__(256) void k_gemm2(const unsigned short* __restrict__ relu1b,
    const float* __restrict__ W2, const float* __restrict__ a2s_w,
    const float* __restrict__ a2d_w, unsigned short* __restrict__ h2b,
    float* __restrict__ as2, float* __restrict__ ad2, int n) {
  __shared__ float w2s[F1 * OUT_DIM];  // 32 KB
  __shared__ float xs[32][72];         // [k][row], 2-way bank alias = free
  const int tid = threadIdx.x;
  const int rb = blockIdx.x * 64;
  for (int i = tid; i < F1 * OUT_DIM; i += 256) w2s[i] = W2[i];
  const int rx = tid >> 3;       // 0..31 -> rows rx, rx+32
  const int cq = tid & 7;        // 0..7  -> cols 4cq..4cq+3
  float accA[4] = {0.f, 0.f, 0.f, 0.f};
  float accB[4] = {0.f, 0.f, 0.f, 0.f};
  for (int kb = 0; kb < F1; kb += 32) {
    __syncthreads();
#pragma unroll
    for (int i = 0; i < 2; ++i) {
      int idx = tid + i * 256;            // 0..511
      int r = idx >> 3, c4 = idx & 7;     // row 0..63, uint2 group (4 k-vals)
      int row = rb + r;
      uint2 u = make_uint2(0u, 0u);
      if (row < n) u = *(const uint2*)&relu1b[(size_t)row * F1 + kb + c4 * 4];
      xs[c4 * 4 + 0][r] = b2fl(u.x); xs[c4 * 4 + 1][r] = b2fh(u.x);
      xs[c4 * 4 + 2][r] = b2fl(u.y); xs[c4 * 4 + 3][r] = b2fh(u.y);
    }
    __syncthreads();
#pragma unroll
    for (int kk = 0; kk < 32; ++kk) {
      const float xa = xs[kk][rx];
      const float xb = xs[kk][rx + 32];
      const float4 wv = *(const float4*)&w2s[(kb + kk) * OUT_DIM + 4 * cq];
      accA[0] += xa * wv.x; accA[1] += xa * wv.y; accA[2] += xa * wv.z; accA[3] += xa * wv.w;
      accB[0] += xb * wv.x; accB[1] += xb * wv.y; accB[2] += xb * wv.z; accB[3] += xb * wv.w;
    }
  }
  const float4 sv = *(const float4*)&a2s_w[4 * cq];
  const float4 dv = *(const float4*)&a2d_w[4 * cq];
  const int rA = rb + rx, rB = rb + rx + 32;
  if (rA < n) {
    ushort4 v; v.x = f2b(accA[0]); v.y = f2b(accA[1]); v.z = f2b(accA[2]); v.w = f2b(accA[3]);
    *(ushort4*)&h2b[(size_t)rA * OUT_DIM + 4 * cq] = v;
  }
  if (rB < n) {
    ushort4 v; v.x = f2b(accB[0]); v.y = f2b(accB[1]); v.z = f2b(accB[2]); v.w = f2b(accB[3]);
    *(ushort4*)&h2b[(size_t)rB * OUT_DIM + 4 * cq] = v;
  }
  float ssA = accA[0] * sv.x + accA[1] * sv.y + accA[2] * sv.z + accA[3] * sv.w;
  float sdA = accA[0] * dv.x + accA[1] * dv.y + accA[2] * dv.z + accA[3] * dv.w;
  float ssB = accB[0] * sv.x + accB[1] * sv.y + accB[2] * sv.z + accB[3] * sv.w;
  float sdB = accB[0] * dv.x + accB[1] * dv.y + accB[2] * dv.z + accB[3] * dv.w;
#pragma unroll
  for (int m = 1; m <= 4; m <<= 1) {
    ssA += __shfl_xor(ssA, m, 64);
    sdA += __shfl_xor(sdA, m, 64);
    ssB += __shfl_xor(ssB, m, 64);
    sdB += __shfl_xor(sdB, m, 64);
  }
  if (cq == 0) {
    if (rA < n) { as2[rA] = ssA; ad2[rA] = sdA; }
    if (rB < n) { as2[rB] = ssB; ad2[rB] = sdB; }
  }
}

// ---- w2 precompute: packed {src, w_bits} per edge (8B coalesced write).
// k_agg2 then reads ONE uint2 per edge instead of csr(16B-stride)+w2(4B). ----
__global__ __launch_bounds__(256) void k_w2(const uint4* __restrict__ csr,
    const float* __restrict__ as2, const float* __restrict__ ad2,
    uint2* __restrict__ sw2, int tot) {
  int e = blockIdx.x * 256 + threadIdx.x;
  if (e >= tot) return;
  uint4 r = csr[e];
  float ev = as2[r.x] + ad2[r.w];
  ev = (ev >= 0.f) ? ev : NEG * ev;
  float w = __expf(ev);
  union { float f; unsigned i; } c; c.f = w;
  sw2[e] = make_uint2(r.x, c.i);
}

// -------- fused GAT layer 2 (bf16 gather, quarter-wave, packed {src,w}) --------
__global__ __launch_bounds__(256) void k_agg2(const unsigned short* __restrict__ h2b,
    const uint2* __restrict__ sw2, const int* __restrict__ offs,
    const float* __restrict__ b2, const float* __restrict__ linW,
    float* __restrict__ score, int n) {
  int node = blockIdx.x * 4 + (threadIdx.x >> 6);
  int lane = threadIdx.x & 63;
  if (node >= n) return;
  const int sub = lane >> 4;
  const int p = lane & 15;
  const int j0 = offs[node], j1 = offs[node + 1];
  float acc0 = 0.f, acc1 = 0.f, den = 0.f;
  union { unsigned i; float f; } cv;
  int jj = j0;
  for (; jj + 8 <= j1; jj += 8) {
    const uint2 rA = sw2[jj + sub];
    const uint2 rB = sw2[jj + 4 + sub];
    cv.i = rA.y; const float wA = cv.f;
    cv.i = rB.y; const float wB = cv.f;
    const unsigned uA = ((const unsigned*)(h2b + (size_t)rA.x * OUT_DIM))[p];
    const unsigned uB = ((const unsigned*)(h2b + (size_t)rB.x * OUT_DIM))[p];
    den += wA; acc0 += wA * b2fl(uA); acc1 += wA * b2fh(uA);
    den += wB; acc0 += wB * b2fl(uB); acc1 += wB * b2fh(uB);
  }
  for (; jj < j1; jj += 4) {
    const int idx = jj + sub;
    const bool valid = idx < j1;
    const uint2 r = sw2[valid ? idx : (j1 - 1)];
    cv.i = r.y; float w = valid ? cv.f : 0.f;
    const unsigned u = ((const unsigned*)(h2b + (size_t)r.x * OUT_DIM))[p];
    den += w; acc0 += w * b2fl(u); acc1 += w * b2fh(u);
  }
  den  += __shfl_xor(den, 16, 64);  den  += __shfl_xor(den, 32, 64);
  acc0 += __shfl_xor(acc0, 16, 64); acc0 += __shfl_xor(acc0, 32, 64);
  acc1 += __shfl_xor(acc1, 16, 64); acc1 += __shfl_xor(acc1, 32, 64);
  const float inv = 1.0f / den;
  float o0 = acc0 * inv + b2[2 * p];
  float o1 = acc1 * inv + b2[2 * p + 1];
  float m = fmaxf(o0, o1);
#pragma unroll
  for (int mm = 1; mm <= 8; mm <<= 1) m = fmaxf(m, __shfl_xor(m, mm, 64));
  float ssum = __expf(o0 - m) + __expf(o1 - m);
#pragma unroll
  for (int mm = 1; mm <= 8; mm <<= 1) ssum += __shfl_xor(ssum, mm, 64);
  const float lse = m + __logf(ssum);
  float sc = (o0 - lse) * linW[2 * p] + (o1 - lse) * linW[2 * p + 1];
#pragma unroll
  for (int mm = 1; mm <= 8; mm <<= 1) sc += __shfl_xor(sc, mm, 64);
  if (lane == 0) score[node] = sc;
}

// -------- pooling: LDS per-graph partials, few global atomics per block --------
__global__ __launch_bounds__(256) void k_pool(const float* __restrict__ score,
    const int* __restrict__ batch, float* __restrict__ gsum,
    float* __restrict__ gcnt, int n) {
  __shared__ float ps[64];
  __shared__ float pc[64];
  const int tid = threadIdx.x;
  if (tid < 64) { ps[tid] = 0.f; pc[tid] = 0.f; }
  __syncthreads();
  int i = blockIdx.x * 256 + tid;
  if (i < n) {
    int g = batch[i];
    atomicAdd(&ps[g], score[i]);
    atomicAdd(&pc[g], 1.0f);
  }
  __syncthreads();
  if (tid < 64 && pc[tid] != 0.f) {
    atomicAdd(&gsum[tid], ps[tid]);
    atomicAdd(&gcnt[tid], pc[tid]);
  }
}

__global__ void k_final(const float* __restrict__ gsum, const float* __restrict__ gcnt,
                        const float* __restrict__ linb, float* __restrict__ out, int g_) {
  int g = threadIdx.x;
  if (g < g_) out[g] = gsum[g] / fmaxf(gcnt[g], 1.0f) + linb[0];
}

extern "C" void kernel_launch(void* const* d_in, const int* in_sizes, int n_in,
                              void* d_out, int out_size, void* d_ws, size_t ws_size,
                              hipStream_t stream) {
  const float* x    = (const float*)d_in[0];
  const int*   adj  = (const int*)d_in[1];
  const int*   batch= (const int*)d_in[2];
  const float* W1   = (const float*)d_in[3];
  const float* a1s  = (const float*)d_in[4];
  const float* a1d  = (const float*)d_in[5];
  const float* b1   = (const float*)d_in[6];
  const float* W2   = (const float*)d_in[7];
  const float* a2s  = (const float*)d_in[8];
  const float* a2d  = (const float*)d_in[9];
  const float* b2   = (const float*)d_in[10];
  const float* linW = (const float*)d_in[11];
  const float* linb = (const float*)d_in[12];

  const int N = in_sizes[0] / IN_DIM;
  const int E = in_sizes[1] / 2;
  const int ET = E + N;
  const int G = out_size;   // 64
  const int NB = (N + 1023) / 1024;
  const int BINW = (N + 7) / 8;

  char* wsb = (char*)d_ws;
  size_t off = 0;
  auto take = [&](size_t bytes) -> char* {
    char* p = wsb + off;
    off += (bytes + 255) & ~(size_t)255;
    return p;
  };
  unsigned char* h1f8  = (unsigned char*)take((size_t)N * F1);
  unsigned short* relu1b= (unsigned short*)take((size_t)N * F1 * 2);
  float* as1    = (float*)take((size_t)N * 4 * 4);
  float* ad1    = (float*)take((size_t)N * 4 * 4);
  unsigned short* h2b = (unsigned short*)take((size_t)N * OUT_DIM * 2);
  float* as2v   = (float*)take((size_t)N * 4);
  float* ad2v   = (float*)take((size_t)N * 4);
  float* score  = (float*)take((size_t)N * 4);
  int*   cnt    = (int*)take((size_t)N * 4);
  int*   offs   = (int*)take((size_t)(N + 1) * 4);
  int*   rank   = (int*)take((size_t)ET * 4);
  uint4* csr    = (uint4*)take((size_t)ET * 16);
  uint2* sw2    = (uint2*)take((size_t)ET * 8);
  int*   bsum   = (int*)take((size_t)(NB + 1) * 4);
  float* gsum   = (float*)take((size_t)G * 4);
  float* gcnt   = (float*)take((size_t)G * 4);
  unsigned short* W1t = (unsigned short*)take((size_t)IN_DIM * F1 * 2);
  (void)ws_size; (void)n_in;

  hipMemsetAsync(cnt, 0, (size_t)N * 4, stream);
  hipMemsetAsync(gsum, 0, (size_t)G * 4, stream);
  hipMemsetAsync(gcnt, 0, (size_t)G * 4, stream);

  dim3 b256(256);
  k_prep<<<dim3((IN_DIM * F1) / 256), b256, 0, stream>>>(W1, W1t);
  k_gemm1<<<dim3((N + 63) / 64, F1 / 64), b256, 0, stream>>>(x, W1t, a1s, a1d, h1f8, as1, ad1, N);
  k_hist<<<dim3((ET + 255) / 256), b256, 0, stream>>>(adj, cnt, rank, E, N);
  k_scan_local<<<dim3(NB), b256, 0, stream>>>(cnt, offs, bsum, N);
  k_scan_bsum<<<1, 64, 0, stream>>>(bsum, NB, offs + N);
  k_scan_add<<<dim3((N + 255) / 256), b256, 0, stream>>>(offs, bsum, N);
  k_scatter<<<dim3(((ET + 255) / 256) * 8), b256, 0, stream>>>(adj, rank, offs, as1, ad1, csr, E, N, BINW);
  k_agg1<<<dim3((N + 3) / 4), b256, 0, stream>>>(h1f8, offs, csr, b1, relu1b, N);
  k_gemm2<<<dim3((N + 63) / 64), b256, 0, stream>>>(relu1b, W2, a2s, a2d, h2b, as2v, ad2v, N);
  k_w2<<<dim3((ET + 255) / 256), b256, 0, stream>>>(csr, as2v, ad2v, sw2, ET);
  k_agg2<<<dim3((N + 3) / 4), b256, 0, stream>>>(h2b, sw2, offs, b2, linW, score, N);
  k_pool<<<dim3((N + 255) / 256), b256, 0, stream>>>(score, batch, gsum, gcnt, N);
  k_final<<<1, 64, 0, stream>>>(gsum, gcnt, linb, (float*)d_out, G);
}

// Round 15
// 277.223 us; speedup vs baseline: 1.1734x; 1.0902x over previous
//
#include <hip/hip_runtime.h>

#define IN_DIM 128
#define F1 256      // HEADS*HID = 4*64
#define HID 64
#define OUT_DIM 32
#define NEG 0.2f
#define PADK 136    // LDS row pitch in bf16 elems (128 + 8): frag reads 2-way alias = free

typedef __attribute__((ext_vector_type(8))) short short8;
typedef __attribute__((ext_vector_type(4))) float v4f;
typedef __attribute__((ext_vector_type(2))) float v2f;

// ---- bf16 helpers ----
__device__ __forceinline__ float b2fl(unsigned u) {
  union { unsigned i; float f; } c; c.i = u << 16; return c.f;
}
__device__ __forceinline__ float b2fh(unsigned u) {
  union { unsigned i; float f; } c; c.i = u & 0xffff0000u; return c.f;
}
__device__ __forceinline__ unsigned short f2b(float f) {
  union { float f; unsigned i; } c; c.f = f;
  unsigned r = c.i + 0x7fffu + ((c.i >> 16) & 1u);   // RNE
  return (unsigned short)(r >> 16);
}

// ---- merged prep + hist: blocks [0,128) transpose W1->W1t bf16,
// blocks [128,160) transpose W2->W2t bf16, rest do hist+rank ----
__global__ __launch_bounds__(256) void k_prep_hist(const float* __restrict__ W1,
    unsigned short* __restrict__ W1t, const float* __restrict__ W2,
    unsigned short* __restrict__ W2t, const int* __restrict__ adj,
    int* __restrict__ cnt, int* __restrict__ rank, int E_, int n) {
  const int b = blockIdx.x;
  if (b < 128) {            // W1t[n][k] = W1[k][n], 32768 elems
    int idx = b * 256 + threadIdx.x;
    int nn = idx >> 7, k = idx & 127;
    W1t[idx] = f2b(W1[(size_t)k * F1 + nn]);
    return;
  }
  if (b < 160) {            // W2t[n][k] = W2[k][n], 8192 elems
    int idx = (b - 128) * 256 + threadIdx.x;
    int nn = idx >> 8, k = idx & 255;
    W2t[idx] = f2b(W2[(size_t)k * OUT_DIM + nn]);
    return;
  }
  int e = (b - 160) * 256 + threadIdx.x;
  int ET = E_ + n;
  if (e >= ET) return;
  int d = (e < E_) ? adj[E_ + e] : (e - E_);
  rank[e] = atomicAdd(&cnt[d], 1);
}

// ------- GEMM1 via MFMA: h1f8[N,256](fp8 e4m3) = bf16(x)[N,128] @ W1[128,256] -------
__global__ __launch_bounds__(256) void k_gemm1(const float* __restrict__ x,
    const unsigned short* __restrict__ W1t,
    const float* __restrict__ a1s_w, const float* __restrict__ a1d_w,
    unsigned char* __restrict__ h1f8, float* __restrict__ as1,
    float* __restrict__ ad1, int n) {
  __shared__ unsigned short xs[64 * PADK];   // 17.4 KB
  __shared__ unsigned short ws[64 * PADK];   // 17.4 KB
  const int tid = threadIdx.x;
  const int rb = blockIdx.x * 64;
  const int head = blockIdx.y;
  const int cb = head * 64;

#pragma unroll
  for (int i = 0; i < 8; ++i) {
    int idx = tid + i * 256;
    int row = idx >> 5, c4 = idx & 31;
    float4 v = make_float4(0.f, 0.f, 0.f, 0.f);
    if (rb + row < n) v = *(const float4*)&x[(size_t)(rb + row) * IN_DIM + c4 * 4];
    ushort4 b; b.x = f2b(v.x); b.y = f2b(v.y); b.z = f2b(v.z); b.w = f2b(v.w);
    *(ushort4*)&xs[row * PADK + c4 * 4] = b;
  }
#pragma unroll
  for (int i = 0; i < 4; ++i) {
    int idx = tid + i * 256;
    int row = idx >> 4, c = idx & 15;
    *(uint4*)&ws[row * PADK + c * 8] =
        *(const uint4*)&W1t[(size_t)(cb + row) * IN_DIM + c * 8];
  }
  __syncthreads();

  const int wv = tid >> 6;
  const int lane = tid & 63;
  const int l15 = lane & 15, quad = lane >> 4;
  v4f acc0 = {0.f, 0.f, 0.f, 0.f}, acc1 = acc0, acc2 = acc0, acc3 = acc0;
#pragma unroll
  for (int kt = 0; kt < 4; ++kt) {
    const int ko = kt * 32 + quad * 8;
    short8 af = *(const short8*)&xs[(wv * 16 + l15) * PADK + ko];
    short8 b0 = *(const short8*)&ws[(l15) * PADK + ko];
    short8 b1 = *(const short8*)&ws[(16 + l15) * PADK + ko];
    short8 b2 = *(const short8*)&ws[(32 + l15) * PADK + ko];
    short8 b3 = *(const short8*)&ws[(48 + l15) * PADK + ko];
    acc0 = __builtin_amdgcn_mfma_f32_16x16x32_bf16(af, b0, acc0, 0, 0, 0);
    acc1 = __builtin_amdgcn_mfma_f32_16x16x32_bf16(af, b1, acc1, 0, 0, 0);
    acc2 = __builtin_amdgcn_mfma_f32_16x16x32_bf16(af, b2, acc2, 0, 0, 0);
    acc3 = __builtin_amdgcn_mfma_f32_16x16x32_bf16(af, b3, acc3, 0, 0, 0);
  }

  const float s0 = a1s_w[cb + l15],      s1 = a1s_w[cb + 16 + l15];
  const float s2 = a1s_w[cb + 32 + l15], s3 = a1s_w[cb + 48 + l15];
  const float d0 = a1d_w[cb + l15],      d1 = a1d_w[cb + 16 + l15];
  const float d2 = a1d_w[cb + 32 + l15], d3 = a1d_w[cb + 48 + l15];
#pragma unroll
  for (int r = 0; r < 4; ++r) {
    const int row = rb + wv * 16 + quad * 4 + r;
    const bool ok = row < n;
    if (ok) {
      size_t base = (size_t)row * F1 + cb;
      int pA = __builtin_amdgcn_cvt_pk_fp8_f32(acc0[r], acc1[r], 0, false);
      int pB = __builtin_amdgcn_cvt_pk_fp8_f32(acc2[r], acc3[r], 0, false);
      h1f8[base + l15]      = (unsigned char)(pA & 0xff);
      h1f8[base + 16 + l15] = (unsigned char)((pA >> 8) & 0xff);
      h1f8[base + 32 + l15] = (unsigned char)(pB & 0xff);
      h1f8[base + 48 + l15] = (unsigned char)((pB >> 8) & 0xff);
    }
    float ds = acc0[r] * s0 + acc1[r] * s1 + acc2[r] * s2 + acc3[r] * s3;
    float dd = acc0[r] * d0 + acc1[r] * d1 + acc2[r] * d2 + acc3[r] * d3;
#pragma unroll
    for (int m = 1; m <= 8; m <<= 1) {
      ds += __shfl_xor(ds, m, 64);
      dd += __shfl_xor(dd, m, 64);
    }
    if (ok && l15 == 0) {
      as1[(size_t)row * 4 + head] = ds;
      ad1[(size_t)row * 4 + head] = dd;
    }
  }
}

__global__ __launch_bounds__(256) void k_scan_local(const int* __restrict__ cnt,
    int* __restrict__ offs, int* __restrict__ bsum, int n) {
  __shared__ int wsums[4];
  const int tid = threadIdx.x;
  const int lane = tid & 63, w = tid >> 6;
  const int base = blockIdx.x * 1024;
  const int i0 = base + tid * 4;
  int v[4];
#pragma unroll
  for (int k = 0; k < 4; ++k) { int i = i0 + k; v[k] = (i < n) ? cnt[i] : 0; }
  int tsum = v[0] + v[1] + v[2] + v[3];
  int incl = tsum;
#pragma unroll
  for (int d = 1; d < 64; d <<= 1) {
    int t = __shfl_up(incl, (unsigned)d, 64);
    if (lane >= d) incl += t;
  }
  if (lane == 63) wsums[w] = incl;
  __syncthreads();
  int pre = 0;
  for (int k = 0; k < w; ++k) pre += wsums[k];
  int run = pre + incl - tsum;
#pragma unroll
  for (int k = 0; k < 4; ++k) { int i = i0 + k; if (i < n) offs[i] = run; run += v[k]; }
  if (tid == 255) bsum[blockIdx.x] = pre + incl;
}

__global__ void k_scan_bsum(int* __restrict__ bsum, int nb, int* __restrict__ offs_n) {
  int lane = threadIdx.x;   // 64 threads
  int carry = 0;
  for (int base = 0; base < nb; base += 64) {
    int i = base + lane;
    int v = (i < nb) ? bsum[i] : 0;
    int incl = v;
#pragma unroll
    for (int d = 1; d < 64; d <<= 1) {
      int t = __shfl_up(incl, (unsigned)d, 64);
      if (lane >= d) incl += t;
    }
    if (i < nb) bsum[i] = carry + incl - v;
    int tot = __shfl(incl, 63, 64);
    carry += tot;
  }
  if (lane == 0) *offs_n = carry;
}

__global__ __launch_bounds__(256) void k_scan_add(int* __restrict__ offs,
    const int* __restrict__ bsum, int n) {
  int i = blockIdx.x * 256 + threadIdx.x;
  if (i < n) offs[i] += bsum[i >> 10];
}

// -------- scatter, atomic-free; rec = {src, w01, w23, dst}; 4 dst-bins --------
// (8 bins halved to 4: per-bin csr region 3.4MB still fits one 4MB L2, but
// the redundant adj/rank stream and early-exit wave overhead halve.)
__global__ __launch_bounds__(256) void k_scatter(const int* __restrict__ adj,
    const int* __restrict__ rank, const int* __restrict__ offs,
    const float* __restrict__ as1, const float* __restrict__ ad1,
    uint4* __restrict__ csr, int E_, int n, int binw) {
  const int bin = blockIdx.x & 3;
  const int chunk = blockIdx.x >> 2;
  const int e = chunk * 256 + threadIdx.x;
  const int ET = E_ + n;
  if (e >= ET) return;
  int d = (e < E_) ? adj[E_ + e] : (e - E_);
  const int lo = bin * binw;
  if (d < lo || d >= lo + binw) return;   // not my bin
  int s = (e < E_) ? adj[e] : d;
  int pos = offs[d] + rank[e];
  const float4 qs = *(const float4*)(as1 + (size_t)s * 4);
  const float4 qd = *(const float4*)(ad1 + (size_t)d * 4);
  float ev, w0, w1, w2, w3;
  ev = qs.x + qd.x; ev = (ev >= 0.f) ? ev : NEG * ev; w0 = __expf(ev);
  ev = qs.y + qd.y; ev = (ev >= 0.f) ? ev : NEG * ev; w1 = __expf(ev);
  ev = qs.z + qd.z; ev = (ev >= 0.f) ? ev : NEG * ev; w2 = __expf(ev);
  ev = qs.w + qd.w; ev = (ev >= 0.f) ? ev : NEG * ev; w3 = __expf(ev);
  uint4 rec;
  rec.x = (unsigned)s;
  rec.y = (unsigned)f2b(w0) | ((unsigned)f2b(w1) << 16);
  rec.z = (unsigned)f2b(w2) | ((unsigned)f2b(w3) << 16);
  rec.w = (unsigned)d;
  csr[pos] = rec;
}

// ------- fused GAT layer 1 (fp8 gather, half-wave edge pairing) -------
__global__ __launch_bounds__(256) void k_agg1(const unsigned char* __restrict__ h1f8,
    const int* __restrict__ offs, const uint4* __restrict__ csr,
    const float* __restrict__ b1, unsigned short* __restrict__ relu1b, int n) {
  int node = blockIdx.x * 4 + (threadIdx.x >> 6);
  int lane = threadIdx.x & 63;
  if (node >= n) return;
  const int sub = lane >> 5;       // which edge of the pair
  const int l = lane & 31;         // feature octet
  const int h = l >> 3;            // head
  const bool hHi = (h & 2) != 0, hOdd = (h & 1) != 0;
  const int j0 = offs[node], j1 = offs[node + 1];
  float a0=0.f,a1=0.f,a2=0.f,a3=0.f,a4=0.f,a5=0.f,a6=0.f,a7=0.f,den=0.f;
  int j = j0;
  for (; j + 4 <= j1; j += 4) {
    const uint4 rA = csr[j + sub];
    const uint4 rB = csr[j + 2 + sub];
    const uint2 uA = ((const uint2*)(h1f8 + (size_t)rA.x * F1))[l];
    const uint2 uB = ((const uint2*)(h1f8 + (size_t)rB.x * F1))[l];
    unsigned ws; float w;
    v2f p0, p1, p2, p3;
    ws = hHi ? rA.z : rA.y; w = hOdd ? b2fh(ws) : b2fl(ws);
    p0 = __builtin_amdgcn_cvt_pk_f32_fp8(uA.x, false);
    p1 = __builtin_amdgcn_cvt_pk_f32_fp8(uA.x, true);
    p2 = __builtin_amdgcn_cvt_pk_f32_fp8(uA.y, false);
    p3 = __builtin_amdgcn_cvt_pk_f32_fp8(uA.y, true);
    den += w;
    a0 += w * p0.x; a1 += w * p0.y; a2 += w * p1.x; a3 += w * p1.y;
    a4 += w * p2.x; a5 += w * p2.y; a6 += w * p3.x; a7 += w * p3.y;
    ws = hHi ? rB.z : rB.y; w = hOdd ? b2fh(ws) : b2fl(ws);
    p0 = __builtin_amdgcn_cvt_pk_f32_fp8(uB.x, false);
    p1 = __builtin_amdgcn_cvt_pk_f32_fp8(uB.x, true);
    p2 = __builtin_amdgcn_cvt_pk_f32_fp8(uB.y, false);
    p3 = __builtin_amdgcn_cvt_pk_f32_fp8(uB.y, true);
    den += w;
    a0 += w * p0.x; a1 += w * p0.y; a2 += w * p1.x; a3 += w * p1.y;
    a4 += w * p2.x; a5 += w * p2.y; a6 += w * p3.x; a7 += w * p3.y;
  }
  for (; j < j1; j += 2) {
    const int idx = j + sub;
    const bool valid = idx < j1;
    const uint4 r = csr[valid ? idx : (j1 - 1)];
    const uint2 u = ((const uint2*)(h1f8 + (size_t)r.x * F1))[l];
    unsigned ws = hHi ? r.z : r.y;
    float w = hOdd ? b2fh(ws) : b2fl(ws);
    if (!valid) w = 0.f;
    v2f p0 = __builtin_amdgcn_cvt_pk_f32_fp8(u.x, false);
    v2f p1 = __builtin_amdgcn_cvt_pk_f32_fp8(u.x, true);
    v2f p2 = __builtin_amdgcn_cvt_pk_f32_fp8(u.y, false);
    v2f p3 = __builtin_amdgcn_cvt_pk_f32_fp8(u.y, true);
    den += w;
    a0 += w * p0.x; a1 += w * p0.y; a2 += w * p1.x; a3 += w * p1.y;
    a4 += w * p2.x; a5 += w * p2.y; a6 += w * p3.x; a7 += w * p3.y;
  }
  den += __shfl_xor(den, 32, 64);
  a0 += __shfl_xor(a0, 32, 64); a1 += __shfl_xor(a1, 32, 64);
  a2 += __shfl_xor(a2, 32, 64); a3 += __shfl_xor(a3, 32, 64);
  a4 += __shfl_xor(a4, 32, 64); a5 += __shfl_xor(a5, 32, 64);
  a6 += __shfl_xor(a6, 32, 64); a7 += __shfl_xor(a7, 32, 64);
  if (sub == 0) {
    const float inv = 1.0f / den;
    const float4 bb0 = ((const float4*)b1)[2 * l];
    const float4 bb1 = ((const float4*)b1)[2 * l + 1];
    ushort4 r0, r1;
    r0.x = f2b(fmaxf(a0 * inv + bb0.x, 0.f));
    r0.y = f2b(fmaxf(a1 * inv + bb0.y, 0.f));
    r0.z = f2b(fmaxf(a2 * inv + bb0.z, 0.f));
    r0.w = f2b(fmaxf(a3 * inv + bb0.w, 0.f));
    r1.x = f2b(fmaxf(a4 * inv + bb1.x, 0.f));
    r1.y = f2b(fmaxf(a5 * inv + bb1.y, 0.f));
    r1.z = f2b(fmaxf(a6 * inv + bb1.z, 0.f));
    r1.w = f2b(fmaxf(a7 * inv + bb1.w, 0.f));
    *(ushort4*)&relu1b[(size_t)node * F1 + 8 * l] = r0;
    *(ushort4*)&relu1b[(size_t)node * F1 + 8 * l + 4] = r1;
  }
}

// ---- GEMM2 via MFMA: h2[N,32] = relu1b(bf16) @ W2t(bf16); fused alpha2 dots ----
// A-frags straight from global (relu1b is bf16 row-major: m=l15, k=quad*8+j);
// B-frags from W2t[n][k] (16 KB, L1-resident). No LDS. 4 waves x 16 rows/block.
__global__ __launch_bounds__(256) void k_gemm2(const unsigned short* __restrict__ relu1b,
    const unsigned short* __restrict__ W2t, const float* __restrict__ a2s_w,
    const float* __restrict__ a2d_w, unsigned short* __restrict__ h2b,
    float* __restrict__ as2, float* __restrict__ ad2, int n) {
  const int tid = threadIdx.x;
  const int wv = tid >> 6, lane = tid & 63;
  const int l15 = lane & 15, quad = lane >> 4;
  const int row0 = blockIdx.x * 64 + wv * 16;
  v4f acc0 = {0.f, 0.f, 0.f, 0.f}, acc1 = acc0;
  const int arow = row0 + l15;
  const bool aok = arow < n;
#pragma unroll
  for (int kt = 0; kt < 8; ++kt) {
    const int ko = kt * 32 + quad * 8;
    short8 af = {0, 0, 0, 0, 0, 0, 0, 0};
    if (aok) af = *(const short8*)&relu1b[(size_t)arow * F1 + ko];
    short8 b0 = *(const short8*)&W2t[(size_t)l15 * F1 + ko];
    short8 b1 = *(const short8*)&W2t[(size_t)(16 + l15) * F1 + ko];
    acc0 = __builtin_amdgcn_mfma_f32_16x16x32_bf16(af, b0, acc0, 0, 0, 0);
    acc1 = __builtin_amdgcn_mfma_f32_16x16x32_bf16(af, b1, acc1, 0, 0, 0);
  }
  const float s0 = a2s_w[l15], s1 = a2s_w[16 + l15];
  const float d0 = a2d_w[l15], d1 = a2d_w[16 + l15];
#pragma unroll
  for (int r = 0; r < 4; ++r) {
    const int row = row0 + quad * 4 + r;
    const bool ok = row < n;
    if (ok) {
      h2b[(size_t)row * OUT_DIM + l15]      = f2b(acc0[r]);
      h2b[(size_t)row * OUT_DIM + 16 + l15] = f2b(acc1[r]);
    }
    float ss = acc0[r] * s0 + acc1[r] * s1;
    float sd = acc0[r] * d0 + acc1[r] * d1;
#pragma unroll
    for (int m = 1; m <= 8; m <<= 1) {
      ss += __shfl_xor(ss, m, 64);
      sd += __shfl_xor(sd, m, 64);
    }
    if (ok && l15 == 0) { as2[row] = ss; ad2[row] = sd; }
  }
}

// ---- w2 precompute: packed {src, w_bits} per edge (8B coalesced write) ----
__global__ __launch_bounds__(256) void k_w2(const uint4* __restrict__ csr,
    const float* __restrict__ as2, const float* __restrict__ ad2,
    uint2* __restrict__ sw2, int tot) {
  int e = blockIdx.x * 256 + threadIdx.x;
  if (e >= tot) return;
  uint4 r = csr[e];
  float ev = as2[r.x] + ad2[r.w];
  ev = (ev >= 0.f) ? ev : NEG * ev;
  float w = __expf(ev);
  union { float f; unsigned i; } c; c.f = w;
  sw2[e] = make_uint2(r.x, c.i);
}

// -------- fused GAT layer 2 (bf16 gather, quarter-wave, packed {src,w}) --------
__global__ __launch_bounds__(256) void k_agg2(const unsigned short* __restrict__ h2b,
    const uint2* __restrict__ sw2, const int* __restrict__ offs,
    const float* __restrict__ b2, const float* __restrict__ linW,
    float* __restrict__ score, int n) {
  int node = blockIdx.x * 4 + (threadIdx.x >> 6);
  int lane = threadIdx.x & 63;
  if (node >= n) return;
  const int sub = lane >> 4;
  const int p = lane & 15;
  const int j0 = offs[node], j1 = offs[node + 1];
  float acc0 = 0.f, acc1 = 0.f, den = 0.f;
  union { unsigned i; float f; } cv;
  int jj = j0;
  for (; jj + 8 <= j1; jj += 8) {
    const uint2 rA = sw2[jj + sub];
    const uint2 rB = sw2[jj + 4 + sub];
    cv.i = rA.y; const float wA = cv.f;
    cv.i = rB.y; const float wB = cv.f;
    const unsigned uA = ((const unsigned*)(h2b + (size_t)rA.x * OUT_DIM))[p];
    const unsigned uB = ((const unsigned*)(h2b + (size_t)rB.x * OUT_DIM))[p];
    den += wA; acc0 += wA * b2fl(uA); acc1 += wA * b2fh(uA);
    den += wB; acc0 += wB * b2fl(uB); acc1 += wB * b2fh(uB);
  }
  for (; jj < j1; jj += 4) {
    const int idx = jj + sub;
    const bool valid = idx < j1;
    const uint2 r = sw2[valid ? idx : (j1 - 1)];
    cv.i = r.y; float w = valid ? cv.f : 0.f;
    const unsigned u = ((const unsigned*)(h2b + (size_t)r.x * OUT_DIM))[p];
    den += w; acc0 += w * b2fl(u); acc1 += w * b2fh(u);
  }
  den  += __shfl_xor(den, 16, 64);  den  += __shfl_xor(den, 32, 64);
  acc0 += __shfl_xor(acc0, 16, 64); acc0 += __shfl_xor(acc0, 32, 64);
  acc1 += __shfl_xor(acc1, 16, 64); acc1 += __shfl_xor(acc1, 32, 64);
  const float inv = 1.0f / den;
  float o0 = acc0 * inv + b2[2 * p];
  float o1 = acc1 * inv + b2[2 * p + 1];
  float m = fmaxf(o0, o1);
#pragma unroll
  for (int mm = 1; mm <= 8; mm <<= 1) m = fmaxf(m, __shfl_xor(m, mm, 64));
  float ssum = __expf(o0 - m) + __expf(o1 - m);
#pragma unroll
  for (int mm = 1; mm <= 8; mm <<= 1) ssum += __shfl_xor(ssum, mm, 64);
  const float lse = m + __logf(ssum);
  float sc = (o0 - lse) * linW[2 * p] + (o1 - lse) * linW[2 * p + 1];
#pragma unroll
  for (int mm = 1; mm <= 8; mm <<= 1) sc += __shfl_xor(sc, mm, 64);
  if (lane == 0) score[node] = sc;
}

// -------- pooling: LDS per-graph partials, few global atomics per block --------
__global__ __launch_bounds__(256) void k_pool(const float* __restrict__ score,
    const int* __restrict__ batch, float* __restrict__ gsum,
    float* __restrict__ gcnt, int n) {
  __shared__ float ps[64];
  __shared__ float pc[64];
  const int tid = threadIdx.x;
  if (tid < 64) { ps[tid] = 0.f; pc[tid] = 0.f; }
  __syncthreads();
  int i = blockIdx.x * 256 + tid;
  if (i < n) {
    int g = batch[i];
    atomicAdd(&ps[g], score[i]);
    atomicAdd(&pc[g], 1.0f);
  }
  __syncthreads();
  if (tid < 64 && pc[tid] != 0.f) {
    atomicAdd(&gsum[tid], ps[tid]);
    atomicAdd(&gcnt[tid], pc[tid]);
  }
}

__global__ void k_final(const float* __restrict__ gsum, const float* __restrict__ gcnt,
                        const float* __restrict__ linb, float* __restrict__ out, int g_) {
  int g = threadIdx.x;
  if (g < g_) out[g] = gsum[g] / fmaxf(gcnt[g], 1.0f) + linb[0];
}

extern "C" void kernel_launch(void* const* d_in, const int* in_sizes, int n_in,
                              void* d_out, int out_size, void* d_ws, size_t ws_size,
                              hipStream_t stream) {
  const float* x    = (const float*)d_in[0];
  const int*   adj  = (const int*)d_in[1];
  const int*   batch= (const int*)d_in[2];
  const float* W1   = (const float*)d_in[3];
  const float* a1s  = (const float*)d_in[4];
  const float* a1d  = (const float*)d_in[5];
  const float* b1   = (const float*)d_in[6];
  const float* W2   = (const float*)d_in[7];
  const float* a2s  = (const float*)d_in[8];
  const float* a2d  = (const float*)d_in[9];
  const float* b2   = (const float*)d_in[10];
  const float* linW = (const float*)d_in[11];
  const float* linb = (const float*)d_in[12];

  const int N = in_sizes[0] / IN_DIM;
  const int E = in_sizes[1] / 2;
  const int ET = E + N;
  const int G = out_size;   // 64
  const int NB = (N + 1023) / 1024;
  const int BINW = (N + 3) / 4;

  char* wsb = (char*)d_ws;
  size_t off = 0;
  auto take = [&](size_t bytes) -> char* {
    char* p = wsb + off;
    off += (bytes + 255) & ~(size_t)255;
    return p;
  };
  unsigned char* h1f8  = (unsigned char*)take((size_t)N * F1);
  unsigned short* relu1b= (unsigned short*)take((size_t)N * F1 * 2);
  float* as1    = (float*)take((size_t)N * 4 * 4);
  float* ad1    = (float*)take((size_t)N * 4 * 4);
  unsigned short* h2b = (unsigned short*)take((size_t)N * OUT_DIM * 2);
  float* as2v   = (float*)take((size_t)N * 4);
  float* ad2v   = (float*)take((size_t)N * 4);
  float* score  = (float*)take((size_t)N * 4);
  int*   cnt    = (int*)take((size_t)N * 4);
  int*   offs   = (int*)take((size_t)(N + 1) * 4);
  int*   rank   = (int*)take((size_t)ET * 4);
  uint4* csr    = (uint4*)take((size_t)ET * 16);
  uint2* sw2    = (uint2*)take((size_t)ET * 8);
  int*   bsum   = (int*)take((size_t)(NB + 1) * 4);
  float* gsum   = (float*)take((size_t)G * 4);
  float* gcnt   = (float*)take((size_t)G * 4);
  unsigned short* W1t = (unsigned short*)take((size_t)IN_DIM * F1 * 2);
  unsigned short* W2t = (unsigned short*)take((size_t)F1 * OUT_DIM * 2);
  (void)ws_size; (void)n_in;

  hipMemsetAsync(cnt, 0, (size_t)N * 4, stream);
  hipMemsetAsync(gsum, 0, (size_t)G * 4, stream);
  hipMemsetAsync(gcnt, 0, (size_t)G * 4, stream);

  dim3 b256(256);
  k_prep_hist<<<dim3(160 + (ET + 255) / 256), b256, 0, stream>>>(
      W1, W1t, W2, W2t, adj, cnt, rank, E, N);
  k_gemm1<<<dim3((N + 63) / 64, F1 / 64), b256, 0, stream>>>(x, W1t, a1s, a1d, h1f8, as1, ad1, N);
  k_scan_local<<<dim3(NB), b256, 0, stream>>>(cnt, offs, bsum, N);
  k_scan_bsum<<<1, 64, 0, stream>>>(bsum, NB, offs + N);
  k_scan_add<<<dim3((N + 255) / 256), b256, 0, stream>>>(offs, bsum, N);
  k_scatter<<<dim3(((ET + 255) / 256) * 4), b256, 0, stream>>>(adj, rank, offs, as1, ad1, csr, E, N, BINW);
  k_agg1<<<dim3((N + 3) / 4), b256, 0, stream>>>(h1f8, offs, csr, b1, relu1b, N);
  k_gemm2<<<dim3((N + 63) / 64), b256, 0, stream>>>(relu1b, W2t, a2s, a2d, h2b, as2v, ad2v, N);
  k_w2<<<dim3((ET + 255) / 256), b256, 0, stream>>>(csr, as2v, ad2v, sw2, ET);
  k_agg2<<<dim3((N + 3) / 4), b256, 0, stream>>>(h2b, sw2, offs, b2, linW, score, N);
  k_pool<<<dim3((N + 255) / 256), b256, 0, stream>>>(score, batch, gsum, gcnt, N);
  k_final<<<1, 64, 0, stream>>>(gsum, gcnt, linb, (float*)d_out, G);
}

// Round 16
// 274.368 us; speedup vs baseline: 1.1856x; 1.0104x over previous
//
#include <hip/hip_runtime.h>

#define IN_DIM 128
#define F1 256      // HEADS*HID = 4*64
#define HID 64
#define OUT_DIM 32
#define NEG 0.2f
#define PADK 136    // LDS row pitch in bf16 elems (128 + 8): frag reads 2-way alias = free

typedef __attribute__((ext_vector_type(8))) short short8;
typedef __attribute__((ext_vector_type(4))) float v4f;
typedef __attribute__((ext_vector_type(2))) float v2f;

// ---- bf16 helpers ----
__device__ __forceinline__ float b2fl(unsigned u) {
  union { unsigned i; float f; } c; c.i = u << 16; return c.f;
}
__device__ __forceinline__ float b2fh(unsigned u) {
  union { unsigned i; float f; } c; c.i = u & 0xffff0000u; return c.f;
}
__device__ __forceinline__ unsigned short f2b(float f) {
  union { float f; unsigned i; } c; c.f = f;
  unsigned r = c.i + 0x7fffu + ((c.i >> 16) & 1u);   // RNE
  return (unsigned short)(r >> 16);
}

// ---- merged prep + hist ----
__global__ __launch_bounds__(256) void k_prep_hist(const float* __restrict__ W1,
    unsigned short* __restrict__ W1t, const float* __restrict__ W2,
    unsigned short* __restrict__ W2t, const int* __restrict__ adj,
    int* __restrict__ cnt, int* __restrict__ rank, int E_, int n) {
  const int b = blockIdx.x;
  if (b < 128) {            // W1t[n][k] = W1[k][n], 32768 elems
    int idx = b * 256 + threadIdx.x;
    int nn = idx >> 7, k = idx & 127;
    W1t[idx] = f2b(W1[(size_t)k * F1 + nn]);
    return;
  }
  if (b < 160) {            // W2t[n][k] = W2[k][n], 8192 elems
    int idx = (b - 128) * 256 + threadIdx.x;
    int nn = idx >> 8, k = idx & 255;
    W2t[idx] = f2b(W2[(size_t)k * OUT_DIM + nn]);
    return;
  }
  int e = (b - 160) * 256 + threadIdx.x;
  int ET = E_ + n;
  if (e >= ET) return;
  int d = (e < E_) ? adj[E_ + e] : (e - E_);
  rank[e] = atomicAdd(&cnt[d], 1);
}

// ------- GEMM1 via MFMA: h1f8[N,256](fp8 e4m3) = bf16(x)[N,128] @ W1[128,256] -------
__global__ __launch_bounds__(256) void k_gemm1(const float* __restrict__ x,
    const unsigned short* __restrict__ W1t,
    const float* __restrict__ a1s_w, const float* __restrict__ a1d_w,
    unsigned char* __restrict__ h1f8, float* __restrict__ as1,
    float* __restrict__ ad1, int n) {
  __shared__ unsigned short xs[64 * PADK];   // 17.4 KB
  __shared__ unsigned short ws[64 * PADK];   // 17.4 KB
  const int tid = threadIdx.x;
  const int rb = blockIdx.x * 64;
  const int head = blockIdx.y;
  const int cb = head * 64;

#pragma unroll
  for (int i = 0; i < 8; ++i) {
    int idx = tid + i * 256;
    int row = idx >> 5, c4 = idx & 31;
    float4 v = make_float4(0.f, 0.f, 0.f, 0.f);
    if (rb + row < n) v = *(const float4*)&x[(size_t)(rb + row) * IN_DIM + c4 * 4];
    ushort4 b; b.x = f2b(v.x); b.y = f2b(v.y); b.z = f2b(v.z); b.w = f2b(v.w);
    *(ushort4*)&xs[row * PADK + c4 * 4] = b;
  }
#pragma unroll
  for (int i = 0; i < 4; ++i) {
    int idx = tid + i * 256;
    int row = idx >> 4, c = idx & 15;
    *(uint4*)&ws[row * PADK + c * 8] =
        *(const uint4*)&W1t[(size_t)(cb + row) * IN_DIM + c * 8];
  }
  __syncthreads();

  const int wv = tid >> 6;
  const int lane = tid & 63;
  const int l15 = lane & 15, quad = lane >> 4;
  v4f acc0 = {0.f, 0.f, 0.f, 0.f}, acc1 = acc0, acc2 = acc0, acc3 = acc0;
#pragma unroll
  for (int kt = 0; kt < 4; ++kt) {
    const int ko = kt * 32 + quad * 8;
    short8 af = *(const short8*)&xs[(wv * 16 + l15) * PADK + ko];
    short8 b0 = *(const short8*)&ws[(l15) * PADK + ko];
    short8 b1 = *(const short8*)&ws[(16 + l15) * PADK + ko];
    short8 b2 = *(const short8*)&ws[(32 + l15) * PADK + ko];
    short8 b3 = *(const short8*)&ws[(48 + l15) * PADK + ko];
    acc0 = __builtin_amdgcn_mfma_f32_16x16x32_bf16(af, b0, acc0, 0, 0, 0);
    acc1 = __builtin_amdgcn_mfma_f32_16x16x32_bf16(af, b1, acc1, 0, 0, 0);
    acc2 = __builtin_amdgcn_mfma_f32_16x16x32_bf16(af, b2, acc2, 0, 0, 0);
    acc3 = __builtin_amdgcn_mfma_f32_16x16x32_bf16(af, b3, acc3, 0, 0, 0);
  }

  const float s0 = a1s_w[cb + l15],      s1 = a1s_w[cb + 16 + l15];
  const float s2 = a1s_w[cb + 32 + l15], s3 = a1s_w[cb + 48 + l15];
  const float d0 = a1d_w[cb + l15],      d1 = a1d_w[cb + 16 + l15];
  const float d2 = a1d_w[cb + 32 + l15], d3 = a1d_w[cb + 48 + l15];
#pragma unroll
  for (int r = 0; r < 4; ++r) {
    const int row = rb + wv * 16 + quad * 4 + r;
    const bool ok = row < n;
    if (ok) {
      size_t base = (size_t)row * F1 + cb;
      int pA = __builtin_amdgcn_cvt_pk_fp8_f32(acc0[r], acc1[r], 0, false);
      int pB = __builtin_amdgcn_cvt_pk_fp8_f32(acc2[r], acc3[r], 0, false);
      h1f8[base + l15]      = (unsigned char)(pA & 0xff);
      h1f8[base + 16 + l15] = (unsigned char)((pA >> 8) & 0xff);
      h1f8[base + 32 + l15] = (unsigned char)(pB & 0xff);
      h1f8[base + 48 + l15] = (unsigned char)((pB >> 8) & 0xff);
    }
    float ds = acc0[r] * s0 + acc1[r] * s1 + acc2[r] * s2 + acc3[r] * s3;
    float dd = acc0[r] * d0 + acc1[r] * d1 + acc2[r] * d2 + acc3[r] * d3;
#pragma unroll
    for (int m = 1; m <= 8; m <<= 1) {
      ds += __shfl_xor(ds, m, 64);
      dd += __shfl_xor(dd, m, 64);
    }
    if (ok && l15 == 0) {
      as1[(size_t)row * 4 + head] = ds;
      ad1[(size_t)row * 4 + head] = dd;
    }
  }
}

__global__ __launch_bounds__(256) void k_scan_local(const int* __restrict__ cnt,
    int* __restrict__ offs, int* __restrict__ bsum, int n) {
  __shared__ int wsums[4];
  const int tid = threadIdx.x;
  const int lane = tid & 63, w = tid >> 6;
  const int base = blockIdx.x * 1024;
  const int i0 = base + tid * 4;
  int v[4];
#pragma unroll
  for (int k = 0; k < 4; ++k) { int i = i0 + k; v[k] = (i < n) ? cnt[i] : 0; }
  int tsum = v[0] + v[1] + v[2] + v[3];
  int incl = tsum;
#pragma unroll
  for (int d = 1; d < 64; d <<= 1) {
    int t = __shfl_up(incl, (unsigned)d, 64);
    if (lane >= d) incl += t;
  }
  if (lane == 63) wsums[w] = incl;
  __syncthreads();
  int pre = 0;
  for (int k = 0; k < w; ++k) pre += wsums[k];
  int run = pre + incl - tsum;
#pragma unroll
  for (int k = 0; k < 4; ++k) { int i = i0 + k; if (i < n) offs[i] = run; run += v[k]; }
  if (tid == 255) bsum[blockIdx.x] = pre + incl;
}

__global__ void k_scan_bsum(int* __restrict__ bsum, int nb, int* __restrict__ offs_n) {
  int lane = threadIdx.x;   // 64 threads
  int carry = 0;
  for (int base = 0; base < nb; base += 64) {
    int i = base + lane;
    int v = (i < nb) ? bsum[i] : 0;
    int incl = v;
#pragma unroll
    for (int d = 1; d < 64; d <<= 1) {
      int t = __shfl_up(incl, (unsigned)d, 64);
      if (lane >= d) incl += t;
    }
    if (i < nb) bsum[i] = carry + incl - v;
    int tot = __shfl(incl, 63, 64);
    carry += tot;
  }
  if (lane == 0) *offs_n = carry;
}

__global__ __launch_bounds__(256) void k_scan_add(int* __restrict__ offs,
    const int* __restrict__ bsum, int n) {
  int i = blockIdx.x * 256 + threadIdx.x;
  if (i < n) offs[i] += bsum[i >> 10];
}

// -------- scatter, atomic-free; rec = {src, w01, w23, dst}; 4 dst-bins --------
__global__ __launch_bounds__(256) void k_scatter(const int* __restrict__ adj,
    const int* __restrict__ rank, const int* __restrict__ offs,
    const float* __restrict__ as1, const float* __restrict__ ad1,
    uint4* __restrict__ csr, int E_, int n, int binw) {
  const int bin = blockIdx.x & 3;
  const int chunk = blockIdx.x >> 2;
  const int e = chunk * 256 + threadIdx.x;
  const int ET = E_ + n;
  if (e >= ET) return;
  int d = (e < E_) ? adj[E_ + e] : (e - E_);
  const int lo = bin * binw;
  if (d < lo || d >= lo + binw) return;   // not my bin
  int s = (e < E_) ? adj[e] : d;
  int pos = offs[d] + rank[e];
  const float4 qs = *(const float4*)(as1 + (size_t)s * 4);
  const float4 qd = *(const float4*)(ad1 + (size_t)d * 4);
  float ev, w0, w1, w2, w3;
  ev = qs.x + qd.x; ev = (ev >= 0.f) ? ev : NEG * ev; w0 = __expf(ev);
  ev = qs.y + qd.y; ev = (ev >= 0.f) ? ev : NEG * ev; w1 = __expf(ev);
  ev = qs.z + qd.z; ev = (ev >= 0.f) ? ev : NEG * ev; w2 = __expf(ev);
  ev = qs.w + qd.w; ev = (ev >= 0.f) ? ev : NEG * ev; w3 = __expf(ev);
  uint4 rec;
  rec.x = (unsigned)s;
  rec.y = (unsigned)f2b(w0) | ((unsigned)f2b(w1) << 16);
  rec.z = (unsigned)f2b(w2) | ((unsigned)f2b(w3) << 16);
  rec.w = (unsigned)d;
  csr[pos] = rec;
}

// ------- fused GAT layer 1 (fp8 gather, QUARTER-wave per edge) -------
// sub=lane>>4 owns one edge; lane p=lane&15 covers feats 16p..16p+15 (one uint4
// of fp8 = whole 256B row per quarter). Head h = p>>2 -> one weight per lane.
// 8 edges/step (2 per quarter) -> ~2.1 serial trips/node, 8 gathers in flight.
// Per-feature edge-accumulation order identical to half-wave version (bitwise same).
__global__ __launch_bounds__(256) void k_agg1(const unsigned char* __restrict__ h1f8,
    const int* __restrict__ offs, const uint4* __restrict__ csr,
    const float* __restrict__ b1, unsigned short* __restrict__ relu1b, int n) {
  int node = blockIdx.x * 4 + (threadIdx.x >> 6);
  int lane = threadIdx.x & 63;
  if (node >= n) return;
  const int sub = lane >> 4;       // edge slot within group of 4
  const int p = lane & 15;         // feature 16-tuple
  const int h = p >> 2;            // head
  const bool hHi = (h & 2) != 0, hOdd = (h & 1) != 0;
  const int j0 = offs[node], j1 = offs[node + 1];
  float a[16];
#pragma unroll
  for (int i = 0; i < 16; ++i) a[i] = 0.f;
  float den = 0.f;
  int j = j0;
  for (; j + 8 <= j1; j += 8) {
    const uint4 rA = csr[j + sub];
    const uint4 rB = csr[j + 4 + sub];
    const uint4 uA = ((const uint4*)(h1f8 + (size_t)rA.x * F1))[p];
    const uint4 uB = ((const uint4*)(h1f8 + (size_t)rB.x * F1))[p];
    unsigned wbits; float w;
    v2f q;
    wbits = hHi ? rA.z : rA.y; w = hOdd ? b2fh(wbits) : b2fl(wbits);
    den += w;
    q = __builtin_amdgcn_cvt_pk_f32_fp8(uA.x, false); a[0] += w * q.x; a[1] += w * q.y;
    q = __builtin_amdgcn_cvt_pk_f32_fp8(uA.x, true);  a[2] += w * q.x; a[3] += w * q.y;
    q = __builtin_amdgcn_cvt_pk_f32_fp8(uA.y, false); a[4] += w * q.x; a[5] += w * q.y;
    q = __builtin_amdgcn_cvt_pk_f32_fp8(uA.y, true);  a[6] += w * q.x; a[7] += w * q.y;
    q = __builtin_amdgcn_cvt_pk_f32_fp8(uA.z, false); a[8] += w * q.x; a[9] += w * q.y;
    q = __builtin_amdgcn_cvt_pk_f32_fp8(uA.z, true);  a[10] += w * q.x; a[11] += w * q.y;
    q = __builtin_amdgcn_cvt_pk_f32_fp8(uA.w, false); a[12] += w * q.x; a[13] += w * q.y;
    q = __builtin_amdgcn_cvt_pk_f32_fp8(uA.w, true);  a[14] += w * q.x; a[15] += w * q.y;
    wbits = hHi ? rB.z : rB.y; w = hOdd ? b2fh(wbits) : b2fl(wbits);
    den += w;
    q = __builtin_amdgcn_cvt_pk_f32_fp8(uB.x, false); a[0] += w * q.x; a[1] += w * q.y;
    q = __builtin_amdgcn_cvt_pk_f32_fp8(uB.x, true);  a[2] += w * q.x; a[3] += w * q.y;
    q = __builtin_amdgcn_cvt_pk_f32_fp8(uB.y, false); a[4] += w * q.x; a[5] += w * q.y;
    q = __builtin_amdgcn_cvt_pk_f32_fp8(uB.y, true);  a[6] += w * q.x; a[7] += w * q.y;
    q = __builtin_amdgcn_cvt_pk_f32_fp8(uB.z, false); a[8] += w * q.x; a[9] += w * q.y;
    q = __builtin_amdgcn_cvt_pk_f32_fp8(uB.z, true);  a[10] += w * q.x; a[11] += w * q.y;
    q = __builtin_amdgcn_cvt_pk_f32_fp8(uB.w, false); a[12] += w * q.x; a[13] += w * q.y;
    q = __builtin_amdgcn_cvt_pk_f32_fp8(uB.w, true);  a[14] += w * q.x; a[15] += w * q.y;
  }
  for (; j < j1; j += 4) {
    const int idx = j + sub;
    const bool valid = idx < j1;
    const uint4 r = csr[valid ? idx : (j1 - 1)];
    const uint4 u = ((const uint4*)(h1f8 + (size_t)r.x * F1))[p];
    unsigned wbits = hHi ? r.z : r.y;
    float w = hOdd ? b2fh(wbits) : b2fl(wbits);
    if (!valid) w = 0.f;
    den += w;
    v2f q;
    q = __builtin_amdgcn_cvt_pk_f32_fp8(u.x, false); a[0] += w * q.x; a[1] += w * q.y;
    q = __builtin_amdgcn_cvt_pk_f32_fp8(u.x, true);  a[2] += w * q.x; a[3] += w * q.y;
    q = __builtin_amdgcn_cvt_pk_f32_fp8(u.y, false); a[4] += w * q.x; a[5] += w * q.y;
    q = __builtin_amdgcn_cvt_pk_f32_fp8(u.y, true);  a[6] += w * q.x; a[7] += w * q.y;
    q = __builtin_amdgcn_cvt_pk_f32_fp8(u.z, false); a[8] += w * q.x; a[9] += w * q.y;
    q = __builtin_amdgcn_cvt_pk_f32_fp8(u.z, true);  a[10] += w * q.x; a[11] += w * q.y;
    q = __builtin_amdgcn_cvt_pk_f32_fp8(u.w, false); a[12] += w * q.x; a[13] += w * q.y;
    q = __builtin_amdgcn_cvt_pk_f32_fp8(u.w, true);  a[14] += w * q.x; a[15] += w * q.y;
  }
  // combine 4 quarter-waves (same p across subs)
  den += __shfl_xor(den, 16, 64); den += __shfl_xor(den, 32, 64);
#pragma unroll
  for (int i = 0; i < 16; ++i) {
    a[i] += __shfl_xor(a[i], 16, 64);
    a[i] += __shfl_xor(a[i], 32, 64);
  }
  if (sub == 0) {
    const float inv = 1.0f / den;
    ushort4 r0, r1, r2, r3;
    const float4 bb0 = ((const float4*)b1)[4 * p + 0];
    const float4 bb1 = ((const float4*)b1)[4 * p + 1];
    const float4 bb2 = ((const float4*)b1)[4 * p + 2];
    const float4 bb3 = ((const float4*)b1)[4 * p + 3];
    r0.x = f2b(fmaxf(a[0] * inv + bb0.x, 0.f));
    r0.y = f2b(fmaxf(a[1] * inv + bb0.y, 0.f));
    r0.z = f2b(fmaxf(a[2] * inv + bb0.z, 0.f));
    r0.w = f2b(fmaxf(a[3] * inv + bb0.w, 0.f));
    r1.x = f2b(fmaxf(a[4] * inv + bb1.x, 0.f));
    r1.y = f2b(fmaxf(a[5] * inv + bb1.y, 0.f));
    r1.z = f2b(fmaxf(a[6] * inv + bb1.z, 0.f));
    r1.w = f2b(fmaxf(a[7] * inv + bb1.w, 0.f));
    r2.x = f2b(fmaxf(a[8] * inv + bb2.x, 0.f));
    r2.y = f2b(fmaxf(a[9] * inv + bb2.y, 0.f));
    r2.z = f2b(fmaxf(a[10] * inv + bb2.z, 0.f));
    r2.w = f2b(fmaxf(a[11] * inv + bb2.w, 0.f));
    r3.x = f2b(fmaxf(a[12] * inv + bb3.x, 0.f));
    r3.y = f2b(fmaxf(a[13] * inv + bb3.y, 0.f));
    r3.z = f2b(fmaxf(a[14] * inv + bb3.z, 0.f));
    r3.w = f2b(fmaxf(a[15] * inv + bb3.w, 0.f));
    size_t base = (size_t)node * F1 + 16 * p;
    *(ushort4*)&relu1b[base + 0]  = r0;
    *(ushort4*)&relu1b[base + 4]  = r1;
    *(ushort4*)&relu1b[base + 8]  = r2;
    *(ushort4*)&relu1b[base + 12] = r3;
  }
}

// ---- GEMM2 via MFMA: h2[N,32] = relu1b(bf16) @ W2t(bf16); fused alpha2 dots ----
__global__ __launch_bounds__(256) void k_gemm2(const unsigned short* __restrict__ relu1b,
    const unsigned short* __restrict__ W2t, const float* __restrict__ a2s_w,
    const float* __restrict__ a2d_w, unsigned short* __restrict__ h2b,
    float* __restrict__ as2, float* __restrict__ ad2, int n) {
  const int tid = threadIdx.x;
  const int wv = tid >> 6, lane = tid & 63;
  const int l15 = lane & 15, quad = lane >> 4;
  const int row0 = blockIdx.x * 64 + wv * 16;
  v4f acc0 = {0.f, 0.f, 0.f, 0.f}, acc1 = acc0;
  const int arow = row0 + l15;
  const bool aok = arow < n;
#pragma unroll
  for (int kt = 0; kt < 8; ++kt) {
    const int ko = kt * 32 + quad * 8;
    short8 af = {0, 0, 0, 0, 0, 0, 0, 0};
    if (aok) af = *(const short8*)&relu1b[(size_t)arow * F1 + ko];
    short8 b0 = *(const short8*)&W2t[(size_t)l15 * F1 + ko];
    short8 b1 = *(const short8*)&W2t[(size_t)(16 + l15) * F1 + ko];
    acc0 = __builtin_amdgcn_mfma_f32_16x16x32_bf16(af, b0, acc0, 0, 0, 0);
    acc1 = __builtin_amdgcn_mfma_f32_16x16x32_bf16(af, b1, acc1, 0, 0, 0);
  }
  const float s0 = a2s_w[l15], s1 = a2s_w[16 + l15];
  const float d0 = a2d_w[l15], d1 = a2d_w[16 + l15];
#pragma unroll
  for (int r = 0; r < 4; ++r) {
    const int row = row0 + quad * 4 + r;
    const bool ok = row < n;
    if (ok) {
      h2b[(size_t)row * OUT_DIM + l15]      = f2b(acc0[r]);
      h2b[(size_t)row * OUT_DIM + 16 + l15] = f2b(acc1[r]);
    }
    float ss = acc0[r] * s0 + acc1[r] * s1;
    float sd = acc0[r] * d0 + acc1[r] * d1;
#pragma unroll
    for (int m = 1; m <= 8; m <<= 1) {
      ss += __shfl_xor(ss, m, 64);
      sd += __shfl_xor(sd, m, 64);
    }
    if (ok && l15 == 0) { as2[row] = ss; ad2[row] = sd; }
  }
}

// ---- w2 precompute: packed {src, w_bits} per edge (8B coalesced write) ----
__global__ __launch_bounds__(256) void k_w2(const uint4* __restrict__ csr,
    const float* __restrict__ as2, const float* __restrict__ ad2,
    uint2* __restrict__ sw2, int tot) {
  int e = blockIdx.x * 256 + threadIdx.x;
  if (e >= tot) return;
  uint4 r = csr[e];
  float ev = as2[r.x] + ad2[r.w];
  ev = (ev >= 0.f) ? ev : NEG * ev;
  float w = __expf(ev);
  union { float f; unsigned i; } c; c.f = w;
  sw2[e] = make_uint2(r.x, c.i);
}

// -------- fused GAT layer 2 (bf16 gather, quarter-wave, packed {src,w}) --------
__global__ __launch_bounds__(256) void k_agg2(const unsigned short* __restrict__ h2b,
    const uint2* __restrict__ sw2, const int* __restrict__ offs,
    const float* __restrict__ b2, const float* __restrict__ linW,
    float* __restrict__ score, int n) {
  int node = blockIdx.x * 4 + (threadIdx.x >> 6);
  int lane = threadIdx.x & 63;
  if (node >= n) return;
  const int sub = lane >> 4;
  const int p = lane & 15;
  const int j0 = offs[node], j1 = offs[node + 1];
  float acc0 = 0.f, acc1 = 0.f, den = 0.f;
  union { unsigned i; float f; } cv;
  int jj = j0;
  for (; jj + 8 <= j1; jj += 8) {
    const uint2 rA = sw2[jj + sub];
    const uint2 rB = sw2[jj + 4 + sub];
    cv.i = rA.y; const float wA = cv.f;
    cv.i = rB.y; const float wB = cv.f;
    const unsigned uA = ((const unsigned*)(h2b + (size_t)rA.x * OUT_DIM))[p];
    const unsigned uB = ((const unsigned*)(h2b + (size_t)rB.x * OUT_DIM))[p];
    den += wA; acc0 += wA * b2fl(uA); acc1 += wA * b2fh(uA);
    den += wB; acc0 += wB * b2fl(uB); acc1 += wB * b2fh(uB);
  }
  for (; jj < j1; jj += 4) {
    const int idx = jj + sub;
    const bool valid = idx < j1;
    const uint2 r = sw2[valid ? idx : (j1 - 1)];
    cv.i = r.y; float w = valid ? cv.f : 0.f;
    const unsigned u = ((const unsigned*)(h2b + (size_t)r.x * OUT_DIM))[p];
    den += w; acc0 += w * b2fl(u); acc1 += w * b2fh(u);
  }
  den  += __shfl_xor(den, 16, 64);  den  += __shfl_xor(den, 32, 64);
  acc0 += __shfl_xor(acc0, 16, 64); acc0 += __shfl_xor(acc0, 32, 64);
  acc1 += __shfl_xor(acc1, 16, 64); acc1 += __shfl_xor(acc1, 32, 64);
  const float inv = 1.0f / den;
  float o0 = acc0 * inv + b2[2 * p];
  float o1 = acc1 * inv + b2[2 * p + 1];
  float m = fmaxf(o0, o1);
#pragma unroll
  for (int mm = 1; mm <= 8; mm <<= 1) m = fmaxf(m, __shfl_xor(m, mm, 64));
  float ssum = __expf(o0 - m) + __expf(o1 - m);
#pragma unroll
  for (int mm = 1; mm <= 8; mm <<= 1) ssum += __shfl_xor(ssum, mm, 64);
  const float lse = m + __logf(ssum);
  float sc = (o0 - lse) * linW[2 * p] + (o1 - lse) * linW[2 * p + 1];
#pragma unroll
  for (int mm = 1; mm <= 8; mm <<= 1) sc += __shfl_xor(sc, mm, 64);
  if (lane == 0) score[node] = sc;
}

// -------- pooling: LDS per-graph partials, few global atomics per block --------
__global__ __launch_bounds__(256) void k_pool(const float* __restrict__ score,
    const int* __restrict__ batch, float* __restrict__ gsum,
    float* __restrict__ gcnt, int n) {
  __shared__ float ps[64];
  __shared__ float pc[64];
  const int tid = threadIdx.x;
  if (tid < 64) { ps[tid] = 0.f; pc[tid] = 0.f; }
  __syncthreads();
  int i = blockIdx.x * 256 + tid;
  if (i < n) {
    int g = batch[i];
    atomicAdd(&ps[g], score[i]);
    atomicAdd(&pc[g], 1.0f);
  }
  __syncthreads();
  if (tid < 64 && pc[tid] != 0.f) {
    atomicAdd(&gsum[tid], ps[tid]);
    atomicAdd(&gcnt[tid], pc[tid]);
  }
}

__global__ void k_final(const float* __restrict__ gsum, const float* __restrict__ gcnt,
                        const float* __restrict__ linb, float* __restrict__ out, int g_) {
  int g = threadIdx.x;
  if (g < g_) out[g] = gsum[g] / fmaxf(gcnt[g], 1.0f) + linb[0];
}

extern "C" void kernel_launch(void* const* d_in, const int* in_sizes, int n_in,
                              void* d_out, int out_size, void* d_ws, size_t ws_size,
                              hipStream_t stream) {
  const float* x    = (const float*)d_in[0];
  const int*   adj  = (const int*)d_in[1];
  const int*   batch= (const int*)d_in[2];
  const float* W1   = (const float*)d_in[3];
  const float* a1s  = (const float*)d_in[4];
  const float* a1d  = (const float*)d_in[5];
  const float* b1   = (const float*)d_in[6];
  const float* W2   = (const float*)d_in[7];
  const float* a2s  = (const float*)d_in[8];
  const float* a2d  = (const float*)d_in[9];
  const float* b2   = (const float*)d_in[10];
  const float* linW = (const float*)d_in[11];
  const float* linb = (const float*)d_in[12];

  const int N = in_sizes[0] / IN_DIM;
  const int E = in_sizes[1] / 2;
  const int ET = E + N;
  const int G = out_size;   // 64
  const int NB = (N + 1023) / 1024;
  const int BINW = (N + 3) / 4;

  char* wsb = (char*)d_ws;
  size_t off = 0;
  auto take = [&](size_t bytes) -> char* {
    char* p = wsb + off;
    off += (bytes + 255) & ~(size_t)255;
    return p;
  };
  unsigned char* h1f8  = (unsigned char*)take((size_t)N * F1);
  unsigned short* relu1b= (unsigned short*)take((size_t)N * F1 * 2);
  float* as1    = (float*)take((size_t)N * 4 * 4);
  float* ad1    = (float*)take((size_t)N * 4 * 4);
  unsigned short* h2b = (unsigned short*)take((size_t)N * OUT_DIM * 2);
  float* as2v   = (float*)take((size_t)N * 4);
  float* ad2v   = (float*)take((size_t)N * 4);
  float* score  = (float*)take((size_t)N * 4);
  int*   cnt    = (int*)take((size_t)N * 4);
  int*   offs   = (int*)take((size_t)(N + 1) * 4);
  int*   rank   = (int*)take((size_t)ET * 4);
  uint4* csr    = (uint4*)take((size_t)ET * 16);
  uint2* sw2    = (uint2*)take((size_t)ET * 8);
  int*   bsum   = (int*)take((size_t)(NB + 1) * 4);
  float* gsum   = (float*)take((size_t)G * 4);
  float* gcnt   = (float*)take((size_t)G * 4);
  unsigned short* W1t = (unsigned short*)take((size_t)IN_DIM * F1 * 2);
  unsigned short* W2t = (unsigned short*)take((size_t)F1 * OUT_DIM * 2);
  (void)ws_size; (void)n_in;

  hipMemsetAsync(cnt, 0, (size_t)N * 4, stream);
  hipMemsetAsync(gsum, 0, (size_t)G * 4, stream);
  hipMemsetAsync(gcnt, 0, (size_t)G * 4, stream);

  dim3 b256(256);
  k_prep_hist<<<dim3(160 + (ET + 255) / 256), b256, 0, stream>>>(
      W1, W1t, W2, W2t, adj, cnt, rank, E, N);
  k_gemm1<<<dim3((N + 63) / 64, F1 / 64), b256, 0, stream>>>(x, W1t, a1s, a1d, h1f8, as1, ad1, N);
  k_scan_local<<<dim3(NB), b256, 0, stream>>>(cnt, offs, bsum, N);
  k_scan_bsum<<<1, 64, 0, stream>>>(bsum, NB, offs + N);
  k_scan_add<<<dim3((N + 255) / 256), b256, 0, stream>>>(offs, bsum, N);
  k_scatter<<<dim3(((ET + 255) / 256) * 4), b256, 0, stream>>>(adj, rank, offs, as1, ad1, csr, E, N, BINW);
  k_agg1<<<dim3((N + 3) / 4), b256, 0, stream>>>(h1f8, offs, csr, b1, relu1b, N);
  k_gemm2<<<dim3((N + 63) / 64), b256, 0, stream>>>(relu1b, W2t, a2s, a2d, h2b, as2v, ad2v, N);
  k_w2<<<dim3((ET + 255) / 256), b256, 0, stream>>>(csr, as2v, ad2v, sw2, ET);
  k_agg2<<<dim3((N + 3) / 4), b256, 0, stream>>>(h2b, sw2, offs, b2, linW, score, N);
  k_pool<<<dim3((N + 255) / 256), b256, 0, stream>>>(score, batch, gsum, gcnt, N);
  k_final<<<1, 64, 0, stream>>>(gsum, gcnt, linb, (float*)d_out, G);
}

// Round 17
// 259.726 us; speedup vs baseline: 1.2525x; 1.0564x over previous
//
#include <hip/hip_runtime.h>

#define IN_DIM 128
#define F1 256      // HEADS*HID = 4*64
#define HID 64
#define OUT_DIM 32
#define NEG 0.2f
#define PADK 136    // LDS row pitch in bf16 elems (128 + 8): frag reads 2-way alias = free

typedef __attribute__((ext_vector_type(8))) short short8;
typedef __attribute__((ext_vector_type(4))) float v4f;
typedef __attribute__((ext_vector_type(2))) float v2f;

// ---- bf16 helpers ----
__device__ __forceinline__ float b2fl(unsigned u) {
  union { unsigned i; float f; } c; c.i = u << 16; return c.f;
}
__device__ __forceinline__ float b2fh(unsigned u) {
  union { unsigned i; float f; } c; c.i = u & 0xffff0000u; return c.f;
}
__device__ __forceinline__ unsigned short f2b(float f) {
  union { float f; unsigned i; } c; c.f = f;
  unsigned r = c.i + 0x7fffu + ((c.i >> 16) & 1u);   // RNE
  return (unsigned short)(r >> 16);
}

// ---- merged prep + hist ----
__global__ __launch_bounds__(256) void k_prep_hist(const float* __restrict__ W1,
    unsigned short* __restrict__ W1t, const float* __restrict__ W2,
    unsigned short* __restrict__ W2t, const int* __restrict__ adj,
    int* __restrict__ cnt, int* __restrict__ rank, int E_, int n) {
  const int b = blockIdx.x;
  if (b < 128) {            // W1t[n][k] = W1[k][n], 32768 elems
    int idx = b * 256 + threadIdx.x;
    int nn = idx >> 7, k = idx & 127;
    W1t[idx] = f2b(W1[(size_t)k * F1 + nn]);
    return;
  }
  if (b < 160) {            // W2t[n][k] = W2[k][n], 8192 elems
    int idx = (b - 128) * 256 + threadIdx.x;
    int nn = idx >> 8, k = idx & 255;
    W2t[idx] = f2b(W2[(size_t)k * OUT_DIM + nn]);
    return;
  }
  int e = (b - 160) * 256 + threadIdx.x;
  int ET = E_ + n;
  if (e >= ET) return;
  int d = (e < E_) ? adj[E_ + e] : (e - E_);
  rank[e] = atomicAdd(&cnt[d], 1);
}

// ------- GEMM1 via MFMA: h1f8[N,256](fp8 e4m3) = bf16(x)[N,128] @ W1[128,256] -------
// R17: x tile staged ONCE per 64-row block; loop over the 4 heads reusing the
// ws buffer (sync-bracketed). Cuts the 4x x re-read (FETCH ~50 -> ~27 MB).
__global__ __launch_bounds__(256) void k_gemm1(const float* __restrict__ x,
    const unsigned short* __restrict__ W1t,
    const float* __restrict__ a1s_w, const float* __restrict__ a1d_w,
    unsigned char* __restrict__ h1f8, float* __restrict__ as1,
    float* __restrict__ ad1, int n) {
  __shared__ unsigned short xs[64 * PADK];   // 17.4 KB
  __shared__ unsigned short ws[64 * PADK];   // 17.4 KB (reused per head)
  const int tid = threadIdx.x;
  const int rb = blockIdx.x * 64;

#pragma unroll
  for (int i = 0; i < 8; ++i) {
    int idx = tid + i * 256;
    int row = idx >> 5, c4 = idx & 31;
    float4 v = make_float4(0.f, 0.f, 0.f, 0.f);
    if (rb + row < n) v = *(const float4*)&x[(size_t)(rb + row) * IN_DIM + c4 * 4];
    ushort4 b; b.x = f2b(v.x); b.y = f2b(v.y); b.z = f2b(v.z); b.w = f2b(v.w);
    *(ushort4*)&xs[row * PADK + c4 * 4] = b;
  }

  const int wv = tid >> 6;
  const int lane = tid & 63;
  const int l15 = lane & 15, quad = lane >> 4;

  for (int head = 0; head < 4; ++head) {
    const int cb = head * 64;
#pragma unroll
    for (int i = 0; i < 4; ++i) {
      int idx = tid + i * 256;
      int row = idx >> 4, c = idx & 15;
      *(uint4*)&ws[row * PADK + c * 8] =
          *(const uint4*)&W1t[(size_t)(cb + row) * IN_DIM + c * 8];
    }
    __syncthreads();

    v4f acc0 = {0.f, 0.f, 0.f, 0.f}, acc1 = acc0, acc2 = acc0, acc3 = acc0;
#pragma unroll
    for (int kt = 0; kt < 4; ++kt) {
      const int ko = kt * 32 + quad * 8;
      short8 af = *(const short8*)&xs[(wv * 16 + l15) * PADK + ko];
      short8 b0 = *(const short8*)&ws[(l15) * PADK + ko];
      short8 b1 = *(const short8*)&ws[(16 + l15) * PADK + ko];
      short8 b2 = *(const short8*)&ws[(32 + l15) * PADK + ko];
      short8 b3 = *(const short8*)&ws[(48 + l15) * PADK + ko];
      acc0 = __builtin_amdgcn_mfma_f32_16x16x32_bf16(af, b0, acc0, 0, 0, 0);
      acc1 = __builtin_amdgcn_mfma_f32_16x16x32_bf16(af, b1, acc1, 0, 0, 0);
      acc2 = __builtin_amdgcn_mfma_f32_16x16x32_bf16(af, b2, acc2, 0, 0, 0);
      acc3 = __builtin_amdgcn_mfma_f32_16x16x32_bf16(af, b3, acc3, 0, 0, 0);
    }

    const float s0 = a1s_w[cb + l15],      s1 = a1s_w[cb + 16 + l15];
    const float s2 = a1s_w[cb + 32 + l15], s3 = a1s_w[cb + 48 + l15];
    const float d0 = a1d_w[cb + l15],      d1 = a1d_w[cb + 16 + l15];
    const float d2 = a1d_w[cb + 32 + l15], d3 = a1d_w[cb + 48 + l15];
#pragma unroll
    for (int r = 0; r < 4; ++r) {
      const int row = rb + wv * 16 + quad * 4 + r;
      const bool ok = row < n;
      if (ok) {
        size_t base = (size_t)row * F1 + cb;
        int pA = __builtin_amdgcn_cvt_pk_fp8_f32(acc0[r], acc1[r], 0, false);
        int pB = __builtin_amdgcn_cvt_pk_fp8_f32(acc2[r], acc3[r], 0, false);
        h1f8[base + l15]      = (unsigned char)(pA & 0xff);
        h1f8[base + 16 + l15] = (unsigned char)((pA >> 8) & 0xff);
        h1f8[base + 32 + l15] = (unsigned char)(pB & 0xff);
        h1f8[base + 48 + l15] = (unsigned char)((pB >> 8) & 0xff);
      }
      float ds = acc0[r] * s0 + acc1[r] * s1 + acc2[r] * s2 + acc3[r] * s3;
      float dd = acc0[r] * d0 + acc1[r] * d1 + acc2[r] * d2 + acc3[r] * d3;
#pragma unroll
      for (int m = 1; m <= 8; m <<= 1) {
        ds += __shfl_xor(ds, m, 64);
        dd += __shfl_xor(dd, m, 64);
      }
      if (ok && l15 == 0) {
        as1[(size_t)row * 4 + head] = ds;
        ad1[(size_t)row * 4 + head] = dd;
      }
    }
    __syncthreads();   // ws reuse barrier (LDS reads done before next stage)
  }
}

// scan phase A: per-1024-chunk local exclusive scan + chunk sums; block 0 also
// zeroes gsum/gcnt (replaces two memset dispatches; k_pool runs much later).
__global__ __launch_bounds__(256) void k_scan_local(const int* __restrict__ cnt,
    int* __restrict__ offs, int* __restrict__ bsum,
    float* __restrict__ gsum, float* __restrict__ gcnt, int n) {
  __shared__ int wsums[4];
  const int tid = threadIdx.x;
  if (blockIdx.x == 0 && tid < 64) { gsum[tid] = 0.f; gcnt[tid] = 0.f; }
  const int lane = tid & 63, w = tid >> 6;
  const int base = blockIdx.x * 1024;
  const int i0 = base + tid * 4;
  int v[4];
#pragma unroll
  for (int k = 0; k < 4; ++k) { int i = i0 + k; v[k] = (i < n) ? cnt[i] : 0; }
  int tsum = v[0] + v[1] + v[2] + v[3];
  int incl = tsum;
#pragma unroll
  for (int d = 1; d < 64; d <<= 1) {
    int t = __shfl_up(incl, (unsigned)d, 64);
    if (lane >= d) incl += t;
  }
  if (lane == 63) wsums[w] = incl;
  __syncthreads();
  int pre = 0;
  for (int k = 0; k < w; ++k) pre += wsums[k];
  int run = pre + incl - tsum;
#pragma unroll
  for (int k = 0; k < 4; ++k) { int i = i0 + k; if (i < n) offs[i] = run; run += v[k]; }
  if (tid == 255) bsum[blockIdx.x] = pre + incl;
}

// scan phase B (merged bsum-scan + add): each 256-elem block spans ONE 1024-chunk,
// so it needs a single prefix value = sum(bsum[0..(blockIdx>>2)-1]). One wave
// scans bsum inline (NB<=64 holds: N=50000 -> NB=49). Block 0 writes offs[n].
__global__ __launch_bounds__(256) void k_scan_add(int* __restrict__ offs,
    const int* __restrict__ bsum, int n, int nb) {
  __shared__ int pre_s, tot_s;
  const int tid = threadIdx.x;
  if (tid < 64) {
    int v = (tid < nb) ? bsum[tid] : 0;
    int incl = v;
#pragma unroll
    for (int d = 1; d < 64; d <<= 1) {
      int t = __shfl_up(incl, (unsigned)d, 64);
      if (tid >= d) incl += t;
    }
    int excl = incl - v;
    int pre = __shfl(excl, blockIdx.x >> 2, 64);
    int tot = __shfl(incl, nb - 1, 64);
    if (tid == 0) { pre_s = pre; tot_s = tot; }
  }
  __syncthreads();
  int i = blockIdx.x * 256 + tid;
  if (i < n) offs[i] += pre_s;
  if (blockIdx.x == 0 && tid == 0) offs[n] = tot_s;
}

// -------- scatter, atomic-free; rec = {src, w01, w23, dst}; 4 dst-bins --------
__global__ __launch_bounds__(256) void k_scatter(const int* __restrict__ adj,
    const int* __restrict__ rank, const int* __restrict__ offs,
    const float* __restrict__ as1, const float* __restrict__ ad1,
    uint4* __restrict__ csr, int E_, int n, int binw) {
  const int bin = blockIdx.x & 3;
  const int chunk = blockIdx.x >> 2;
  const int e = chunk * 256 + threadIdx.x;
  const int ET = E_ + n;
  if (e >= ET) return;
  int d = (e < E_) ? adj[E_ + e] : (e - E_);
  const int lo = bin * binw;
  if (d < lo || d >= lo + binw) return;   // not my bin
  int s = (e < E_) ? adj[e] : d;
  int pos = offs[d] + rank[e];
  const float4 qs = *(const float4*)(as1 + (size_t)s * 4);
  const float4 qd = *(const float4*)(ad1 + (size_t)d * 4);
  float ev, w0, w1, w2, w3;
  ev = qs.x + qd.x; ev = (ev >= 0.f) ? ev : NEG * ev; w0 = __expf(ev);
  ev = qs.y + qd.y; ev = (ev >= 0.f) ? ev : NEG * ev; w1 = __expf(ev);
  ev = qs.z + qd.z; ev = (ev >= 0.f) ? ev : NEG * ev; w2 = __expf(ev);
  ev = qs.w + qd.w; ev = (ev >= 0.f) ? ev : NEG * ev; w3 = __expf(ev);
  uint4 rec;
  rec.x = (unsigned)s;
  rec.y = (unsigned)f2b(w0) | ((unsigned)f2b(w1) << 16);
  rec.z = (unsigned)f2b(w2) | ((unsigned)f2b(w3) << 16);
  rec.w = (unsigned)d;
  csr[pos] = rec;
}

// ------- fused GAT layer 1 (fp8 gather, quarter-wave per edge) -------
__global__ __launch_bounds__(256) void k_agg1(const unsigned char* __restrict__ h1f8,
    const int* __restrict__ offs, const uint4* __restrict__ csr,
    const float* __restrict__ b1, unsigned short* __restrict__ relu1b, int n) {
  int node = blockIdx.x * 4 + (threadIdx.x >> 6);
  int lane = threadIdx.x & 63;
  if (node >= n) return;
  const int sub = lane >> 4;       // edge slot within group of 4
  const int p = lane & 15;         // feature 16-tuple
  const int h = p >> 2;            // head
  const bool hHi = (h & 2) != 0, hOdd = (h & 1) != 0;
  const int j0 = offs[node], j1 = offs[node + 1];
  float a[16];
#pragma unroll
  for (int i = 0; i < 16; ++i) a[i] = 0.f;
  float den = 0.f;
  int j = j0;
  for (; j + 8 <= j1; j += 8) {
    const uint4 rA = csr[j + sub];
    const uint4 rB = csr[j + 4 + sub];
    const uint4 uA = ((const uint4*)(h1f8 + (size_t)rA.x * F1))[p];
    const uint4 uB = ((const uint4*)(h1f8 + (size_t)rB.x * F1))[p];
    unsigned wbits; float w;
    v2f q;
    wbits = hHi ? rA.z : rA.y; w = hOdd ? b2fh(wbits) : b2fl(wbits);
    den += w;
    q = __builtin_amdgcn_cvt_pk_f32_fp8(uA.x, false); a[0] += w * q.x; a[1] += w * q.y;
    q = __builtin_amdgcn_cvt_pk_f32_fp8(uA.x, true);  a[2] += w * q.x; a[3] += w * q.y;
    q = __builtin_amdgcn_cvt_pk_f32_fp8(uA.y, false); a[4] += w * q.x; a[5] += w * q.y;
    q = __builtin_amdgcn_cvt_pk_f32_fp8(uA.y, true);  a[6] += w * q.x; a[7] += w * q.y;
    q = __builtin_amdgcn_cvt_pk_f32_fp8(uA.z, false); a[8] += w * q.x; a[9] += w * q.y;
    q = __builtin_amdgcn_cvt_pk_f32_fp8(uA.z, true);  a[10] += w * q.x; a[11] += w * q.y;
    q = __builtin_amdgcn_cvt_pk_f32_fp8(uA.w, false); a[12] += w * q.x; a[13] += w * q.y;
    q = __builtin_amdgcn_cvt_pk_f32_fp8(uA.w, true);  a[14] += w * q.x; a[15] += w * q.y;
    wbits = hHi ? rB.z : rB.y; w = hOdd ? b2fh(wbits) : b2fl(wbits);
    den += w;
    q = __builtin_amdgcn_cvt_pk_f32_fp8(uB.x, false); a[0] += w * q.x; a[1] += w * q.y;
    q = __builtin_amdgcn_cvt_pk_f32_fp8(uB.x, true);  a[2] += w * q.x; a[3] += w * q.y;
    q = __builtin_amdgcn_cvt_pk_f32_fp8(uB.y, false); a[4] += w * q.x; a[5] += w * q.y;
    q = __builtin_amdgcn_cvt_pk_f32_fp8(uB.y, true);  a[6] += w * q.x; a[7] += w * q.y;
    q = __builtin_amdgcn_cvt_pk_f32_fp8(uB.z, false); a[8] += w * q.x; a[9] += w * q.y;
    q = __builtin_amdgcn_cvt_pk_f32_fp8(uB.z, true);  a[10] += w * q.x; a[11] += w * q.y;
    q = __builtin_amdgcn_cvt_pk_f32_fp8(uB.w, false); a[12] += w * q.x; a[13] += w * q.y;
    q = __builtin_amdgcn_cvt_pk_f32_fp8(uB.w, true);  a[14] += w * q.x; a[15] += w * q.y;
  }
  for (; j < j1; j += 4) {
    const int idx = j + sub;
    const bool valid = idx < j1;
    const uint4 r = csr[valid ? idx : (j1 - 1)];
    const uint4 u = ((const uint4*)(h1f8 + (size_t)r.x * F1))[p];
    unsigned wbits = hHi ? r.z : r.y;
    float w = hOdd ? b2fh(wbits) : b2fl(wbits);
    if (!valid) w = 0.f;
    den += w;
    v2f q;
    q = __builtin_amdgcn_cvt_pk_f32_fp8(u.x, false); a[0] += w * q.x; a[1] += w * q.y;
    q = __builtin_amdgcn_cvt_pk_f32_fp8(u.x, true);  a[2] += w * q.x; a[3] += w * q.y;
    q = __builtin_amdgcn_cvt_pk_f32_fp8(u.y, false); a[4] += w * q.x; a[5] += w * q.y;
    q = __builtin_amdgcn_cvt_pk_f32_fp8(u.y, true);  a[6] += w * q.x; a[7] += w * q.y;
    q = __builtin_amdgcn_cvt_pk_f32_fp8(u.z, false); a[8] += w * q.x; a[9] += w * q.y;
    q = __builtin_amdgcn_cvt_pk_f32_fp8(u.z, true);  a[10] += w * q.x; a[11] += w * q.y;
    q = __builtin_amdgcn_cvt_pk_f32_fp8(u.w, false); a[12] += w * q.x; a[13] += w * q.y;
    q = __builtin_amdgcn_cvt_pk_f32_fp8(u.w, true);  a[14] += w * q.x; a[15] += w * q.y;
  }
  den += __shfl_xor(den, 16, 64); den += __shfl_xor(den, 32, 64);
#pragma unroll
  for (int i = 0; i < 16; ++i) {
    a[i] += __shfl_xor(a[i], 16, 64);
    a[i] += __shfl_xor(a[i], 32, 64);
  }
  if (sub == 0) {
    const float inv = 1.0f / den;
    ushort4 r0, r1, r2, r3;
    const float4 bb0 = ((const float4*)b1)[4 * p + 0];
    const float4 bb1 = ((const float4*)b1)[4 * p + 1];
    const float4 bb2 = ((const float4*)b1)[4 * p + 2];
    const float4 bb3 = ((const float4*)b1)[4 * p + 3];
    r0.x = f2b(fmaxf(a[0] * inv + bb0.x, 0.f));
    r0.y = f2b(fmaxf(a[1] * inv + bb0.y, 0.f));
    r0.z = f2b(fmaxf(a[2] * inv + bb0.z, 0.f));
    r0.w = f2b(fmaxf(a[3] * inv + bb0.w, 0.f));
    r1.x = f2b(fmaxf(a[4] * inv + bb1.x, 0.f));
    r1.y = f2b(fmaxf(a[5] * inv + bb1.y, 0.f));
    r1.z = f2b(fmaxf(a[6] * inv + bb1.z, 0.f));
    r1.w = f2b(fmaxf(a[7] * inv + bb1.w, 0.f));
    r2.x = f2b(fmaxf(a[8] * inv + bb2.x, 0.f));
    r2.y = f2b(fmaxf(a[9] * inv + bb2.y, 0.f));
    r2.z = f2b(fmaxf(a[10] * inv + bb2.z, 0.f));
    r2.w = f2b(fmaxf(a[11] * inv + bb2.w, 0.f));
    r3.x = f2b(fmaxf(a[12] * inv + bb3.x, 0.f));
    r3.y = f2b(fmaxf(a[13] * inv + bb3.y, 0.f));
    r3.z = f2b(fmaxf(a[14] * inv + bb3.z, 0.f));
    r3.w = f2b(fmaxf(a[15] * inv + bb3.w, 0.f));
    size_t base = (size_t)node * F1 + 16 * p;
    *(ushort4*)&relu1b[base + 0]  = r0;
    *(ushort4*)&relu1b[base + 4]  = r1;
    *(ushort4*)&relu1b[base + 8]  = r2;
    *(ushort4*)&relu1b[base + 12] = r3;
  }
}

// ---- GEMM2 via MFMA: h2[N,32] = relu1b(bf16) @ W2t(bf16); fused alpha2 dots ----
__global__ __launch_bounds__(256) void k_gemm2(const unsigned short* __restrict__ relu1b,
    const unsigned short* __restrict__ W2t, const float* __restrict__ a2s_w,
    const float* __restrict__ a2d_w, unsigned short* __restrict__ h2b,
    float* __restrict__ as2, float* __restrict__ ad2, int n) {
  const int tid = threadIdx.x;
  const int wv = tid >> 6, lane = tid & 63;
  const int l15 = lane & 15, quad = lane >> 4;
  const int row0 = blockIdx.x * 64 + wv * 16;
  v4f acc0 = {0.f, 0.f, 0.f, 0.f}, acc1 = acc0;
  const int arow = row0 + l15;
  const bool aok = arow < n;
#pragma unroll
  for (int kt = 0; kt < 8; ++kt) {
    const int ko = kt * 32 + quad * 8;
    short8 af = {0, 0, 0, 0, 0, 0, 0, 0};
    if (aok) af = *(const short8*)&relu1b[(size_t)arow * F1 + ko];
    short8 b0 = *(const short8*)&W2t[(size_t)l15 * F1 + ko];
    short8 b1 = *(const short8*)&W2t[(size_t)(16 + l15) * F1 + ko];
    acc0 = __builtin_amdgcn_mfma_f32_16x16x32_bf16(af, b0, acc0, 0, 0, 0);
    acc1 = __builtin_amdgcn_mfma_f32_16x16x32_bf16(af, b1, acc1, 0, 0, 0);
  }
  const float s0 = a2s_w[l15], s1 = a2s_w[16 + l15];
  const float d0 = a2d_w[l15], d1 = a2d_w[16 + l15];
#pragma unroll
  for (int r = 0; r < 4; ++r) {
    const int row = row0 + quad * 4 + r;
    const bool ok = row < n;
    if (ok) {
      h2b[(size_t)row * OUT_DIM + l15]      = f2b(acc0[r]);
      h2b[(size_t)row * OUT_DIM + 16 + l15] = f2b(acc1[r]);
    }
    float ss = acc0[r] * s0 + acc1[r] * s1;
    float sd = acc0[r] * d0 + acc1[r] * d1;
#pragma unroll
    for (int m = 1; m <= 8; m <<= 1) {
      ss += __shfl_xor(ss, m, 64);
      sd += __shfl_xor(sd, m, 64);
    }
    if (ok && l15 == 0) { as2[row] = ss; ad2[row] = sd; }
  }
}

// ---- w2 precompute: packed {src, w_bits} per edge (8B coalesced write) ----
__global__ __launch_bounds__(256) void k_w2(const uint4* __restrict__ csr,
    const float* __restrict__ as2, const float* __restrict__ ad2,
    uint2* __restrict__ sw2, int tot) {
  int e = blockIdx.x * 256 + threadIdx.x;
  if (e >= tot) return;
  uint4 r = csr[e];
  float ev = as2[r.x] + ad2[r.w];
  ev = (ev >= 0.f) ? ev : NEG * ev;
  float w = __expf(ev);
  union { float f; unsigned i; } c; c.f = w;
  sw2[e] = make_uint2(r.x, c.i);
}

// -------- fused GAT layer 2 (bf16 gather, quarter-wave, packed {src,w}) --------
__global__ __launch_bounds__(256) void k_agg2(const unsigned short* __restrict__ h2b,
    const uint2* __restrict__ sw2, const int* __restrict__ offs,
    const float* __restrict__ b2, const float* __restrict__ linW,
    float* __restrict__ score, int n) {
  int node = blockIdx.x * 4 + (threadIdx.x >> 6);
  int lane = threadIdx.x & 63;
  if (node >= n) return;
  const int sub = lane >> 4;
  const int p = lane & 15;
  const int j0 = offs[node], j1 = offs[node + 1];
  float acc0 = 0.f, acc1 = 0.f, den = 0.f;
  union { unsigned i; float f; } cv;
  int jj = j0;
  for (; jj + 8 <= j1; jj += 8) {
    const uint2 rA = sw2[jj + sub];
    const uint2 rB = sw2[jj + 4 + sub];
    cv.i = rA.y; const float wA = cv.f;
    cv.i = rB.y; const float wB = cv.f;
    const unsigned uA = ((const unsigned*)(h2b + (size_t)rA.x * OUT_DIM))[p];
    const unsigned uB = ((const unsigned*)(h2b + (size_t)rB.x * OUT_DIM))[p];
    den += wA; acc0 += wA * b2fl(uA); acc1 += wA * b2fh(uA);
    den += wB; acc0 += wB * b2fl(uB); acc1 += wB * b2fh(uB);
  }
  for (; jj < j1; jj += 4) {
    const int idx = jj + sub;
    const bool valid = idx < j1;
    const uint2 r = sw2[valid ? idx : (j1 - 1)];
    cv.i = r.y; float w = valid ? cv.f : 0.f;
    const unsigned u = ((const unsigned*)(h2b + (size_t)r.x * OUT_DIM))[p];
    den += w; acc0 += w * b2fl(u); acc1 += w * b2fh(u);
  }
  den  += __shfl_xor(den, 16, 64);  den  += __shfl_xor(den, 32, 64);
  acc0 += __shfl_xor(acc0, 16, 64); acc0 += __shfl_xor(acc0, 32, 64);
  acc1 += __shfl_xor(acc1, 16, 64); acc1 += __shfl_xor(acc1, 32, 64);
  const float inv = 1.0f / den;
  float o0 = acc0 * inv + b2[2 * p];
  float o1 = acc1 * inv + b2[2 * p + 1];
  float m = fmaxf(o0, o1);
#pragma unroll
  for (int mm = 1; mm <= 8; mm <<= 1) m = fmaxf(m, __shfl_xor(m, mm, 64));
  float ssum = __expf(o0 - m) + __expf(o1 - m);
#pragma unroll
  for (int mm = 1; mm <= 8; mm <<= 1) ssum += __shfl_xor(ssum, mm, 64);
  const float lse = m + __logf(ssum);
  float sc = (o0 - lse) * linW[2 * p] + (o1 - lse) * linW[2 * p + 1];
#pragma unroll
  for (int mm = 1; mm <= 8; mm <<= 1) sc += __shfl_xor(sc, mm, 64);
  if (lane == 0) score[node] = sc;
}

// -------- pooling: LDS per-graph partials, few global atomics per block --------
__global__ __launch_bounds__(256) void k_pool(const float* __restrict__ score,
    const int* __restrict__ batch, float* __restrict__ gsum,
    float* __restrict__ gcnt, int n) {
  __shared__ float ps[64];
  __shared__ float pc[64];
  const int tid = threadIdx.x;
  if (tid < 64) { ps[tid] = 0.f; pc[tid] = 0.f; }
  __syncthreads();
  int i = blockIdx.x * 256 + tid;
  if (i < n) {
    int g = batch[i];
    atomicAdd(&ps[g], score[i]);
    atomicAdd(&pc[g], 1.0f);
  }
  __syncthreads();
  if (tid < 64 && pc[tid] != 0.f) {
    atomicAdd(&gsum[tid], ps[tid]);
    atomicAdd(&gcnt[tid], pc[tid]);
  }
}

__global__ void k_final(const float* __restrict__ gsum, const float* __restrict__ gcnt,
                        const float* __restrict__ linb, float* __restrict__ out, int g_) {
  int g = threadIdx.x;
  if (g < g_) out[g] = gsum[g] / fmaxf(gcnt[g], 1.0f) + linb[0];
}

extern "C" void kernel_launch(void* const* d_in, const int* in_sizes, int n_in,
                              void* d_out, int out_size, void* d_ws, size_t ws_size,
                              hipStream_t stream) {
  const float* x    = (const float*)d_in[0];
  const int*   adj  = (const int*)d_in[1];
  const int*   batch= (const int*)d_in[2];
  const float* W1   = (const float*)d_in[3];
  const float* a1s  = (const float*)d_in[4];
  const float* a1d  = (const float*)d_in[5];
  const float* b1   = (const float*)d_in[6];
  const float* W2   = (const float*)d_in[7];
  const float* a2s  = (const float*)d_in[8];
  const float* a2d  = (const float*)d_in[9];
  const float* b2   = (const float*)d_in[10];
  const float* linW = (const float*)d_in[11];
  const float* linb = (const float*)d_in[12];

  const int N = in_sizes[0] / IN_DIM;
  const int E = in_sizes[1] / 2;
  const int ET = E + N;
  const int G = out_size;   // 64
  const int NB = (N + 1023) / 1024;   // must be <= 64 for merged scan (N=50000 -> 49)
  const int BINW = (N + 3) / 4;

  char* wsb = (char*)d_ws;
  size_t off = 0;
  auto take = [&](size_t bytes) -> char* {
    char* p = wsb + off;
    off += (bytes + 255) & ~(size_t)255;
    return p;
  };
  unsigned char* h1f8  = (unsigned char*)take((size_t)N * F1);
  unsigned short* relu1b= (unsigned short*)take((size_t)N * F1 * 2);
  float* as1    = (float*)take((size_t)N * 4 * 4);
  float* ad1    = (float*)take((size_t)N * 4 * 4);
  unsigned short* h2b = (unsigned short*)take((size_t)N * OUT_DIM * 2);
  float* as2v   = (float*)take((size_t)N * 4);
  float* ad2v   = (float*)take((size_t)N * 4);
  float* score  = (float*)take((size_t)N * 4);
  int*   cnt    = (int*)take((size_t)N * 4);
  int*   offs   = (int*)take((size_t)(N + 1) * 4);
  int*   rank   = (int*)take((size_t)ET * 4);
  uint4* csr    = (uint4*)take((size_t)ET * 16);
  uint2* sw2    = (uint2*)take((size_t)ET * 8);
  int*   bsum   = (int*)take((size_t)(NB + 1) * 4);
  float* gsum   = (float*)take((size_t)G * 4);
  float* gcnt   = (float*)take((size_t)G * 4);
  unsigned short* W1t = (unsigned short*)take((size_t)IN_DIM * F1 * 2);
  unsigned short* W2t = (unsigned short*)take((size_t)F1 * OUT_DIM * 2);
  (void)ws_size; (void)n_in;

  hipMemsetAsync(cnt, 0, (size_t)N * 4, stream);

  dim3 b256(256);
  k_prep_hist<<<dim3(160 + (ET + 255) / 256), b256, 0, stream>>>(
      W1, W1t, W2, W2t, adj, cnt, rank, E, N);
  k_gemm1<<<dim3((N + 63) / 64), b256, 0, stream>>>(x, W1t, a1s, a1d, h1f8, as1, ad1, N);
  k_scan_local<<<dim3(NB), b256, 0, stream>>>(cnt, offs, bsum, gsum, gcnt, N);
  k_scan_add<<<dim3((N + 255) / 256), b256, 0, stream>>>(offs, bsum, N, NB);
  k_scatter<<<dim3(((ET + 255) / 256) * 4), b256, 0, stream>>>(adj, rank, offs, as1, ad1, csr, E, N, BINW);
  k_agg1<<<dim3((N + 3) / 4), b256, 0, stream>>>(h1f8, offs, csr, b1, relu1b, N);
  k_gemm2<<<dim3((N + 63) / 64), b256, 0, stream>>>(relu1b, W2t, a2s, a2d, h2b, as2v, ad2v, N);
  k_w2<<<dim3((ET + 255) / 256), b256, 0, stream>>>(csr, as2v, ad2v, sw2, ET);
  k_agg2<<<dim3((N + 3) / 4), b256, 0, stream>>>(h2b, sw2, offs, b2, linW, score, N);
  k_pool<<<dim3((N + 255) / 256), b256, 0, stream>>>(score, batch, gsum, gcnt, N);
  k_final<<<1, 64, 0, stream>>>(gsum, gcnt, linb, (float*)d_out, G);
}